// Round 3
// baseline (1370.262 us; speedup 1.0000x reference)
//
#include <hip/hip_runtime.h>
#include <hip/hip_bf16.h>
#include <math.h>

// CBiAFormerBlock fused implementation, round 3.
// Change vs r2: ALL d_in tensors read as float32 and d_out written as float32,
// per the reference dtypes (setup_inputs is all jnp.float32). r1/r2 read the
// f32 buffers as bf16 -> garbage halves decode as NaN -> the observed NaN.
// Internal workspace layout identical to r2 (32.6 MB, bf16 intermediates).
//
// B=2, C=256, H=W=64, HEADS=8 (HC=32), HG=2 (GC=128), R=1024, NW=64, WT=64.
// Key trick: grid_sample is linear in the image; k/v 1x1 convs are linear in
// channels with per-group grids => Kimg/Vimg = k_w/v_w applied to xa per
// group, pixel-major (bg,hw,o); attention gathers 32 contiguous channels per
// (head, corner). Avoids the 134MB samp tensor and 8x of the k/v GEMM FLOPs.

typedef __hip_bfloat16 bf16;

__device__ __forceinline__ float cvt(float x) { return x; }
__device__ __forceinline__ float cvt(bf16 x) { return __bfloat162float(x); }
__device__ __forceinline__ float gelu_f(float x) {
  return 0.5f * x * (1.0f + erff(x * 0.7071067811865475f));
}

// ---------------- LayerNorm over channel axis (NCHW, C=256, HW=4096) -------
// 32 positions per block (t&31 = pos for coalescing), 8 thread-groups x 32ch.
// T = input element type (float for LN1 on x, bf16 for LN2 on internal x2).
template<typename T>
__global__ __launch_bounds__(256) void ln_kernel(
    const T* __restrict__ x, const float* __restrict__ g,
    const float* __restrict__ bta, bf16* __restrict__ out)
{
  __shared__ float s1[8][32];
  __shared__ float s2[8][32];
  int t = threadIdx.x;
  int pos = t & 31, cs = t >> 5;
  int p = blockIdx.x * 32 + pos;          // global position 0..8191
  int bb = p >> 12, hw = p & 4095;
  const T* xp = x + (size_t)bb * 256 * 4096 + hw;
  float sum = 0.f, ss = 0.f;
  for (int i = 0; i < 32; ++i) {
    float v = cvt(xp[(size_t)(cs * 32 + i) * 4096]);
    sum += v; ss += v * v;
  }
  s1[cs][pos] = sum; s2[cs][pos] = ss;
  __syncthreads();
  if (cs == 0) {
    float S = 0.f, Q = 0.f;
    for (int i = 0; i < 8; ++i) { S += s1[i][pos]; Q += s2[i][pos]; }
    float mu = S * (1.f / 256.f);
    float var = Q * (1.f / 256.f) - mu * mu;
    s1[0][pos] = mu;
    s2[0][pos] = rsqrtf(var + 1e-5f);
  }
  __syncthreads();
  float mu = s1[0][pos], rs = s2[0][pos];
  for (int i = 0; i < 32; ++i) {
    int c = cs * 32 + i;
    float v = cvt(xp[(size_t)c * 4096]);
    out[((size_t)bb * 256 + c) * 4096 + hw] =
        __float2bfloat16((v - mu) * rs * g[c] + bta[c]);
  }
}

// ---------------- Tiled GEMM: out = A(f32 weights, MxK, lda) @ B(bf16, KxN) -
// 64x128 tile, 256 threads, 4x8 micro-tile, stride-16 lanes. f32 accumulate.
// OUTM: 2 = bf16 [m*N+n], 3 = bf16 transposed [n*M+m], 4 = f32 [m*N+n].
// RESM: 0 none, 1 f32 residual (input x), 2 bf16 residual (internal).
// ACT: 1 = exact GELU (pre-residual).
template<int OUTM, int RESM, int ACT>
__global__ __launch_bounds__(256) void gemm_kernel(
    const float* __restrict__ A, const bf16* __restrict__ B,
    const float* __restrict__ bias, const void* __restrict__ res,
    void* __restrict__ out, int M, int N, int K, int lda,
    long long Bz, long long resz, long long outz)
{
  constexpr int BM = 64, BN = 128, BK = 16;
  __shared__ float As[BK][BM + 4];   // transposed: As[k][m]
  __shared__ float Bs[BK][BN + 4];
  int t = threadIdx.x;
  int tx = t & 15, ty = t >> 4;
  int m0 = blockIdx.y * BM, n0 = blockIdx.x * BN;
  int z = blockIdx.z;
  const bf16* Bp = B + (long long)z * Bz + n0;
  float acc[4][8];
#pragma unroll
  for (int i = 0; i < 4; ++i)
#pragma unroll
    for (int j = 0; j < 8; ++j) acc[i][j] = 0.f;

  for (int k0 = 0; k0 < K; k0 += BK) {
#pragma unroll
    for (int i = 0; i < 4; ++i) {
      int idx = t + i * 256;
      int m = idx >> 4, k = idx & 15;
      As[k][m] = A[(size_t)(m0 + m) * lda + k0 + k];
    }
#pragma unroll
    for (int i = 0; i < 8; ++i) {
      int idx = t + i * 256;
      int k = idx >> 7, n = idx & 127;
      Bs[k][n] = cvt(Bp[(size_t)(k0 + k) * N + n]);
    }
    __syncthreads();
#pragma unroll
    for (int k = 0; k < BK; ++k) {
      float av[4], bv[8];
#pragma unroll
      for (int i = 0; i < 4; ++i) av[i] = As[k][ty + i * 16];
#pragma unroll
      for (int j = 0; j < 8; ++j) bv[j] = Bs[k][tx + j * 16];
#pragma unroll
      for (int i = 0; i < 4; ++i)
#pragma unroll
        for (int j = 0; j < 8; ++j) acc[i][j] += av[i] * bv[j];
    }
    __syncthreads();
  }
#pragma unroll
  for (int i = 0; i < 4; ++i) {
    int m = m0 + ty + i * 16;
    float bs = bias ? bias[m] : 0.f;
#pragma unroll
    for (int j = 0; j < 8; ++j) {
      int n = n0 + tx + j * 16;
      float v = acc[i][j] + bs;
      if constexpr (ACT == 1) v = gelu_f(v);
      if constexpr (RESM == 1)
        v += ((const float*)res)[(size_t)((long long)z * resz) + (size_t)m * N + n];
      if constexpr (RESM == 2)
        v += cvt(((const bf16*)res)[(size_t)((long long)z * resz) + (size_t)m * N + n]);
      if constexpr (OUTM == 2)
        ((bf16*)out)[(size_t)((long long)z * outz) + (size_t)m * N + n] = __float2bfloat16(v);
      if constexpr (OUTM == 3)
        ((bf16*)out)[(size_t)((long long)z * outz) + (size_t)n * M + m] = __float2bfloat16(v);
      if constexpr (OUTM == 4)
        ((float*)out)[(size_t)((long long)z * outz) + (size_t)m * N + n] = v;
    }
  }
}

// ---------------- depthwise 3x3 stride-2 pad-1 conv (4,128,Hi,Wi) ----------
template<typename T>
__global__ __launch_bounds__(256) void dwconv_kernel(
    const T* __restrict__ in, const float* __restrict__ wgt,
    float* __restrict__ out, int Hi, int Wi, int Ho, int Wo, int fuse,
    const float* __restrict__ bg_, const float* __restrict__ bb_,
    const float* __restrict__ bm_, const float* __restrict__ bv_)
{
  int idx = blockIdx.x * 256 + threadIdx.x;
  int total = 4 * 128 * Ho * Wo;
  if (idx >= total) return;
  int ow = idx % Wo;
  int oh = (idx / Wo) % Ho;
  int c  = (idx / (Wo * Ho)) % 128;
  int bgi = idx / (Wo * Ho * 128);
  const T* ip = in + ((size_t)bgi * 128 + c) * Hi * Wi;
  float acc = 0.f;
#pragma unroll
  for (int ky = 0; ky < 3; ++ky) {
    int ih = oh * 2 - 1 + ky;
    if ((unsigned)ih >= (unsigned)Hi) continue;
#pragma unroll
    for (int kx = 0; kx < 3; ++kx) {
      int iw = ow * 2 - 1 + kx;
      if ((unsigned)iw >= (unsigned)Wi) continue;
      acc += wgt[c * 9 + ky * 3 + kx] * cvt(ip[ih * Wi + iw]);
    }
  }
  if (fuse) {
    acc = (acc - bm_[c]) * rsqrtf(bv_[c] + 1e-5f) * bg_[c] + bb_[c];
    acc = gelu_f(acc);
  }
  out[idx] = acc;
}

// ---------------- offset head: off4_w @ o -> tanh -> grid (pixel coords) ----
// rows/cols[bg][r][nw] in PIXEL units: (grid+1)*0.5*63. Kept f32.
__global__ __launch_bounds__(256) void offgrid_kernel(
    const float* __restrict__ o, const float* __restrict__ w4,
    float* __restrict__ rows, float* __restrict__ cols)
{
  int idx = blockIdx.x * 256 + threadIdx.x;   // 4*2*1024*64 = 524288 total
  int nw = idx & 63;
  int r = (idx >> 6) & 1023;
  int coord = (idx >> 16) & 1;
  int bg = idx >> 17;
  const float* op = o + (size_t)bg * 8192 + nw;
  const float* wp = w4 + ((size_t)coord * 1024 + r) * 128;
  float acc = 0.f;
  for (int c = 0; c < 128; ++c) acc += wp[c] * op[c * 64];
  float val = tanhf(acc) * (2.0f / 64.0f);        // ranges * FACTOR
  int rc = coord ? (r & 31) : (r >> 5);
  float ref = rc * (4.0f / 63.0f) - 1.0f;         // i*STRIDE/(H-1)*2 - 1
  float pix = (val + ref + 1.0f) * 31.5f;         // (g+1)*0.5*(64-1)
  (coord ? cols : rows)[(size_t)bg * 65536 + r * 64 + nw] = pix;
}

// ---------------- fused deformable window attention ------------------------
// One block per (b, head, nw). Online softmax over R=1024 in chunks of 64.
__global__ __launch_bounds__(256) void attn_kernel(
    const bf16* __restrict__ qbuf, const bf16* __restrict__ Kimg,
    const bf16* __restrict__ Vimg, const float* __restrict__ rowsb,
    const float* __restrict__ colsb, const float* __restrict__ kb,
    const float* __restrict__ vb, const float* __restrict__ pe,
    bf16* __restrict__ aout)
{
  constexpr int RC = 64;
  __shared__ __attribute__((aligned(16))) float wq[64][33];      // [qt][hc], pre-scaled
  __shared__ __attribute__((aligned(16))) float kks[32][RC + 4]; // [hc][rr]
  __shared__ __attribute__((aligned(16))) float vvs[32][RC + 4];
  __shared__ __attribute__((aligned(16))) float Ps[RC][65];      // [rr][qt]
  __shared__ __attribute__((aligned(16))) float pes[70][72];     // posembed window
  __shared__ float red[4][64];
  __shared__ float m_s[64], l_s[64], alph[64];
  // total LDS ~= 64.4 KB

  int blk = blockIdx.x;
  int nw = blk & 63, head = (blk >> 6) & 7, b = blk >> 9;
  int wh = nw >> 3, ww = nw & 7;
  int t = threadIdx.x;
  int lane = t & 63, wave = t >> 6;
  int qc0 = head * 32;

  for (int i = t; i < 64 * 32; i += 256) {
    int hc = i >> 6, qt = i & 63;
    int h = wh * 8 + (qt >> 3), w = ww * 8 + (qt & 7);
    wq[qt][hc] = cvt(qbuf[((size_t)b * 256 + qc0 + hc) * 4096 + h * 64 + w]) * 0.0625f;
  }
  int ry0 = 56 - wh * 8, rx0 = 56 - ww * 8;   // pe row/col base, always in [0,125]
  for (int i = t; i < 70 * 70; i += 256) {
    int yy = i / 70, xx = i % 70;
    pes[yy][xx] = pe[(size_t)head * 16129 + (ry0 + yy) * 127 + rx0 + xx];
  }
  if (t < 64) { m_s[t] = -1e30f; l_s[t] = 0.f; }
  float kbias = kb[qc0 + (t & 31)];
  float vbias = vb[qc0 + (t & 31)];
  float oacc[8] = {0, 0, 0, 0, 0, 0, 0, 0};
  __syncthreads();

  float wqr[32];
#pragma unroll
  for (int hc = 0; hc < 32; ++hc) wqr[hc] = wq[lane][hc];
  int qh = lane >> 3, qw = lane & 7;

  for (int rc0 = 0; rc0 < 1024; rc0 += RC) {
    // ---- stage kk/vv: thread = (hc = t&31, rowgroup = t>>5), 8 passes ----
    {
      int hc = t & 31;
      const bf16* Kb = Kimg + qc0 + hc;
      const bf16* Vb = Vimg + qc0 + hc;
      for (int it = 0; it < RC / 8; ++it) {
        int rr = it * 8 + (t >> 5);
        int r = rc0 + rr;
        float aK = kbias, aV = vbias;
#pragma unroll
        for (int g = 0; g < 2; ++g) {
          int bg = b * 2 + g;
          float rowf = rowsb[(size_t)bg * 65536 + r * 64 + nw];
          float colf = colsb[(size_t)bg * 65536 + r * 64 + nw];
          float r0f = floorf(rowf), c0f = floorf(colf);
          float wr = rowf - r0f, wc = colf - c0f;
          int r0 = (int)r0f, c0 = (int)c0f;
          size_t pb = (size_t)bg * 4096 * 256;
          bool rv0 = ((unsigned)r0 < 64u), rv1 = ((unsigned)(r0 + 1) < 64u);
          bool cv0 = ((unsigned)c0 < 64u), cv1 = ((unsigned)(c0 + 1) < 64u);
          float w00 = (1.f - wr) * (1.f - wc), w01 = (1.f - wr) * wc;
          float w10 = wr * (1.f - wc), w11 = wr * wc;
          if (rv0 && cv0) { size_t o = pb + (size_t)(r0 * 64 + c0) * 256;           aK += w00 * cvt(Kb[o]); aV += w00 * cvt(Vb[o]); }
          if (rv0 && cv1) { size_t o = pb + (size_t)(r0 * 64 + c0 + 1) * 256;       aK += w01 * cvt(Kb[o]); aV += w01 * cvt(Vb[o]); }
          if (rv1 && cv0) { size_t o = pb + (size_t)((r0 + 1) * 64 + c0) * 256;     aK += w10 * cvt(Kb[o]); aV += w10 * cvt(Vb[o]); }
          if (rv1 && cv1) { size_t o = pb + (size_t)((r0 + 1) * 64 + c0 + 1) * 256; aK += w11 * cvt(Kb[o]); aV += w11 * cvt(Vb[o]); }
        }
        kks[hc][rr] = aK; vvs[hc][rr] = aV;
      }
    }
    __syncthreads();
    // ---- scores: wave handles rr = wave*16..+15, lane = query ----
    float s[16];
#pragma unroll
    for (int k = 0; k < 16; ++k) {
      int r = rc0 + wave * 16 + k;
      int rrow = r >> 5, rcol = r & 31;
      s[k] = pes[2 * rrow + 7 - qh][2 * rcol + 7 - qw];
    }
#pragma unroll
    for (int hc = 0; hc < 32; ++hc) {
      float wv = wqr[hc];
      const float4* krow = reinterpret_cast<const float4*>(&kks[hc][wave * 16]);
#pragma unroll
      for (int k4 = 0; k4 < 4; ++k4) {
        float4 kv = krow[k4];
        s[4 * k4 + 0] += wv * kv.x;
        s[4 * k4 + 1] += wv * kv.y;
        s[4 * k4 + 2] += wv * kv.z;
        s[4 * k4 + 3] += wv * kv.w;
      }
    }
    float cmax = -1e30f;
#pragma unroll
    for (int k = 0; k < 16; ++k) cmax = fmaxf(cmax, s[k]);
    red[wave][lane] = cmax;
    __syncthreads();
    if (wave == 0) {
      float cm = fmaxf(fmaxf(red[0][lane], red[1][lane]),
                       fmaxf(red[2][lane], red[3][lane]));
      float mold = m_s[lane];
      float mnew = fmaxf(mold, cm);
      float a = __expf(mold - mnew);
      alph[lane] = a;
      m_s[lane] = mnew;
      l_s[lane] *= a;
    }
    __syncthreads();
    float mnew = m_s[lane];
    float psum = 0.f;
#pragma unroll
    for (int k = 0; k < 16; ++k) {
      float p = __expf(s[k] - mnew);
      Ps[wave * 16 + k][lane] = p;
      psum += p;
    }
    red[wave][lane] = psum;
    float a = alph[lane];
#pragma unroll
    for (int j = 0; j < 8; ++j) oacc[j] *= a;
    __syncthreads();
    if (wave == 0)
      l_s[lane] += red[0][lane] + red[1][lane] + red[2][lane] + red[3][lane];
    // ---- O += P @ V^T : thread = (q=lane, hc = wave*8+j) ----
#pragma unroll
    for (int r4 = 0; r4 < RC / 4; ++r4) {
      float p0 = Ps[r4 * 4 + 0][lane];
      float p1 = Ps[r4 * 4 + 1][lane];
      float p2 = Ps[r4 * 4 + 2][lane];
      float p3 = Ps[r4 * 4 + 3][lane];
#pragma unroll
      for (int j = 0; j < 8; ++j) {
        const float4 vv4 = *reinterpret_cast<const float4*>(&vvs[wave * 8 + j][r4 * 4]);
        oacc[j] += p0 * vv4.x + p1 * vv4.y + p2 * vv4.z + p3 * vv4.w;
      }
    }
    __syncthreads();
  }
  float linv = 1.0f / l_s[lane];
  int h = wh * 8 + qh, w = ww * 8 + qw;
#pragma unroll
  for (int j = 0; j < 8; ++j) {
    aout[((size_t)b * 256 + qc0 + wave * 8 + j) * 4096 + h * 64 + w] =
        __float2bfloat16(oacc[j] * linv);
  }
}

// ---------------------------------------------------------------------------
extern "C" void kernel_launch(void* const* d_in, const int* in_sizes, int n_in,
                              void* d_out, int out_size, void* d_ws, size_t ws_size,
                              hipStream_t stream) {
  (void)in_sizes; (void)n_in; (void)out_size; (void)ws_size;
  const float* x     = (const float*)d_in[0];
  const float* ln1g  = (const float*)d_in[1];
  const float* ln1b  = (const float*)d_in[2];
  const float* q_w   = (const float*)d_in[3];
  const float* q_b   = (const float*)d_in[4];
  const float* k_w   = (const float*)d_in[5];
  const float* k_b   = (const float*)d_in[6];
  const float* v_w   = (const float*)d_in[7];
  const float* v_b   = (const float*)d_in[8];
  const float* off1w = (const float*)d_in[9];
  const float* off2w = (const float*)d_in[10];
  const float* off3w = (const float*)d_in[11];
  const float* bng   = (const float*)d_in[12];
  const float* bnb   = (const float*)d_in[13];
  const float* bnm   = (const float*)d_in[14];
  const float* bnv   = (const float*)d_in[15];
  const float* off4w = (const float*)d_in[16];
  const float* pe    = (const float*)d_in[17];
  const float* pjw   = (const float*)d_in[18];
  const float* pjb   = (const float*)d_in[19];
  const float* ln2g  = (const float*)d_in[20];
  const float* ln2b  = (const float*)d_in[21];
  const float* w1    = (const float*)d_in[22];
  const float* b1    = (const float*)d_in[23];
  const float* w2    = (const float*)d_in[24];
  const float* b2    = (const float*)d_in[25];
  float* outp = (float*)d_out;

  // compact workspace arena: ~32.6 MB, all offsets 16B-aligned
  char* W = (char*)d_ws;
  bf16*  xa   = (bf16*) (W + 0);          // 2,097,152 el (4MB)  LN1 out; reused as aout
  bf16*  qb   = (bf16*) (W + 4194304);    // 2,097,152 el (4MB)  q; reused as xm
  float* dw1  = (float*)(W + 8388608);    //   524,288 el (2MB)
  float* dw2  = (float*)(W + 10485760);   //   131,072 el (512KB)
  float* dw3  = (float*)(W + 11010048);   //    32,768 el (128KB)
  float* rows = (float*)(W + 11141120);   //   262,144 el (1MB)
  float* cols = (float*)(W + 12189696);   //   262,144 el (1MB)
  bf16*  Kimg = (bf16*) (W + 13238272);   // 4,194,304 el (8MB) (bg,hw,o) pixel-major
  bf16*  Vimg = (bf16*) (W + 21626880);   // 4,194,304 el (8MB)
  bf16*  x2   = (bf16*) (W + 30015488);   // 2,097,152 el (4MB)
  bf16*  aout = xa;                       // xa dead after Kimg/Vimg GEMMs
  bf16*  xm   = qb;                       // q dead after attention
  bf16*  hdn  = Kimg;                     // 8,388,608 el (16MB) over Kimg+Vimg (dead after attn)

  // 1. LN1 (x is f32 input)
  ln_kernel<float><<<256, 256, 0, stream>>>(x, ln1g, ln1b, xa);
  // 2. q = q_w @ xa + q_b (bf16 out)
  gemm_kernel<2, 0, 0><<<dim3(32, 4, 2), 256, 0, stream>>>(
      q_w, xa, q_b, nullptr, qb, 256, 4096, 256, 256, 1048576LL, 0LL, 1048576LL);
  // 3. offset branch: 3x depthwise stride-2, last fused BN+GELU
  dwconv_kernel<bf16><<<2048, 256, 0, stream>>>(qb, off1w, dw1, 64, 64, 32, 32, 0,
                                                nullptr, nullptr, nullptr, nullptr);
  dwconv_kernel<float><<<512, 256, 0, stream>>>(dw1, off2w, dw2, 32, 32, 16, 16, 0,
                                                nullptr, nullptr, nullptr, nullptr);
  dwconv_kernel<float><<<128, 256, 0, stream>>>(dw2, off3w, dw3, 16, 16, 8, 8, 1,
                                                bng, bnb, bnm, bnv);
  // 4. offsets -> sampling grid (pixel coords, f32)
  offgrid_kernel<<<2048, 256, 0, stream>>>(dw3, off4w, rows, cols);
  // 5. Kimg/Vimg: per-group channel-mixed images, pixel-major bf16 (bg,hw,o)
  gemm_kernel<3, 0, 0><<<dim3(32, 4, 2), 256, 0, stream>>>(
      k_w,       xa,          nullptr, nullptr, Kimg,           256, 4096, 128, 256, 1048576LL, 0LL, 2097152LL);
  gemm_kernel<3, 0, 0><<<dim3(32, 4, 2), 256, 0, stream>>>(
      k_w + 128, xa + 524288, nullptr, nullptr, Kimg + 1048576, 256, 4096, 128, 256, 1048576LL, 0LL, 2097152LL);
  gemm_kernel<3, 0, 0><<<dim3(32, 4, 2), 256, 0, stream>>>(
      v_w,       xa,          nullptr, nullptr, Vimg,           256, 4096, 128, 256, 1048576LL, 0LL, 2097152LL);
  gemm_kernel<3, 0, 0><<<dim3(32, 4, 2), 256, 0, stream>>>(
      v_w + 128, xa + 524288, nullptr, nullptr, Vimg + 1048576, 256, 4096, 128, 256, 1048576LL, 0LL, 2097152LL);
  // 6. fused deformable window attention (writes aout = xa; xa dead)
  attn_kernel<<<1024, 256, 0, stream>>>(qb, Kimg, Vimg, rows, cols, k_b, v_b, pe, aout);
  // 7. proj + residual(x, f32) -> x2 (bf16)
  gemm_kernel<2, 1, 0><<<dim3(32, 4, 2), 256, 0, stream>>>(
      pjw, aout, pjb, (const void*)x, x2, 256, 4096, 256, 256, 1048576LL, 1048576LL, 1048576LL);
  // 8. LN2 (x2 is internal bf16)
  ln_kernel<bf16><<<256, 256, 0, stream>>>(x2, ln2g, ln2b, xm);
  // 9. MLP1 + GELU -> hdn (bf16, over Kimg/Vimg region)
  gemm_kernel<2, 0, 1><<<dim3(32, 16, 2), 256, 0, stream>>>(
      w1, xm, b1, nullptr, hdn, 1024, 4096, 256, 256, 1048576LL, 0LL, 4194304LL);
  // 10. MLP2 + residual(x2, bf16) -> f32 d_out
  gemm_kernel<4, 2, 0><<<dim3(32, 4, 2), 256, 0, stream>>>(
      w2, hdn, b2, (const void*)x2, outp, 256, 4096, 1024, 1024, 4194304LL, 1048576LL, 1048576LL);
}

// Round 4
// 812.476 us; speedup vs baseline: 1.6865x; 1.6865x over previous
//
#include <hip/hip_runtime.h>
#include <hip/hip_bf16.h>
#include <math.h>

// CBiAFormerBlock fused implementation, round 4.
// Change vs r3 (PASS, 1370us): attention path restructured.
//  - New gather_kernel materializes kk/vv[b][nw][r][256ch] bf16 ONCE
//    (r3 re-did the bilinear gather per head = 8x redundant VALU + scatter).
//  - attn_kernel v2: MFMA (mfma_f32_16x16x32_bf16) for S=Q.K^T and O+=P.V,
//    register-resident online softmax (quad-local shfl_xor butterflies),
//    P routed through LDS (D-layout -> A-layout). LDS 63KB -> 44KB (3 blk/CU).
// Everything else byte-identical to r3 (known good).

typedef __hip_bfloat16 bf16;
typedef __bf16 bf16x8 __attribute__((ext_vector_type(8)));
typedef float f32x4 __attribute__((ext_vector_type(4)));

union U16x8 { uint4 u4; unsigned short us[8]; };

__device__ __forceinline__ float cvt(float x) { return x; }
__device__ __forceinline__ float cvt(bf16 x) { return __bfloat162float(x); }
__device__ __forceinline__ float b2f(unsigned short u) {
  union { float f; unsigned int v; } x; x.v = ((unsigned int)u) << 16; return x.f;
}
__device__ __forceinline__ unsigned short f2b(float f) {
  bf16 h = __float2bfloat16(f);
  return *reinterpret_cast<unsigned short*>(&h);
}
__device__ __forceinline__ float gelu_f(float x) {
  return 0.5f * x * (1.0f + erff(x * 0.7071067811865475f));
}

// ---------------- LayerNorm over channel axis (NCHW, C=256, HW=4096) -------
template<typename T>
__global__ __launch_bounds__(256) void ln_kernel(
    const T* __restrict__ x, const float* __restrict__ g,
    const float* __restrict__ bta, bf16* __restrict__ out)
{
  __shared__ float s1[8][32];
  __shared__ float s2[8][32];
  int t = threadIdx.x;
  int pos = t & 31, cs = t >> 5;
  int p = blockIdx.x * 32 + pos;
  int bb = p >> 12, hw = p & 4095;
  const T* xp = x + (size_t)bb * 256 * 4096 + hw;
  float sum = 0.f, ss = 0.f;
  for (int i = 0; i < 32; ++i) {
    float v = cvt(xp[(size_t)(cs * 32 + i) * 4096]);
    sum += v; ss += v * v;
  }
  s1[cs][pos] = sum; s2[cs][pos] = ss;
  __syncthreads();
  if (cs == 0) {
    float S = 0.f, Q = 0.f;
    for (int i = 0; i < 8; ++i) { S += s1[i][pos]; Q += s2[i][pos]; }
    float mu = S * (1.f / 256.f);
    float var = Q * (1.f / 256.f) - mu * mu;
    s1[0][pos] = mu;
    s2[0][pos] = rsqrtf(var + 1e-5f);
  }
  __syncthreads();
  float mu = s1[0][pos], rs = s2[0][pos];
  for (int i = 0; i < 32; ++i) {
    int c = cs * 32 + i;
    float v = cvt(xp[(size_t)c * 4096]);
    out[((size_t)bb * 256 + c) * 4096 + hw] =
        __float2bfloat16((v - mu) * rs * g[c] + bta[c]);
  }
}

// ---------------- Tiled GEMM: out = A(f32 weights, MxK, lda) @ B(bf16, KxN) -
// OUTM: 2 = bf16 [m*N+n], 3 = bf16 transposed [n*M+m], 4 = f32 [m*N+n].
// RESM: 0 none, 1 f32 residual, 2 bf16 residual. ACT: 1 = exact GELU.
template<int OUTM, int RESM, int ACT>
__global__ __launch_bounds__(256) void gemm_kernel(
    const float* __restrict__ A, const bf16* __restrict__ B,
    const float* __restrict__ bias, const void* __restrict__ res,
    void* __restrict__ out, int M, int N, int K, int lda,
    long long Bz, long long resz, long long outz)
{
  constexpr int BM = 64, BN = 128, BK = 16;
  __shared__ float As[BK][BM + 4];
  __shared__ float Bs[BK][BN + 4];
  int t = threadIdx.x;
  int tx = t & 15, ty = t >> 4;
  int m0 = blockIdx.y * BM, n0 = blockIdx.x * BN;
  int z = blockIdx.z;
  const bf16* Bp = B + (long long)z * Bz + n0;
  float acc[4][8];
#pragma unroll
  for (int i = 0; i < 4; ++i)
#pragma unroll
    for (int j = 0; j < 8; ++j) acc[i][j] = 0.f;

  for (int k0 = 0; k0 < K; k0 += BK) {
#pragma unroll
    for (int i = 0; i < 4; ++i) {
      int idx = t + i * 256;
      int m = idx >> 4, k = idx & 15;
      As[k][m] = A[(size_t)(m0 + m) * lda + k0 + k];
    }
#pragma unroll
    for (int i = 0; i < 8; ++i) {
      int idx = t + i * 256;
      int k = idx >> 7, n = idx & 127;
      Bs[k][n] = cvt(Bp[(size_t)(k0 + k) * N + n]);
    }
    __syncthreads();
#pragma unroll
    for (int k = 0; k < BK; ++k) {
      float av[4], bv[8];
#pragma unroll
      for (int i = 0; i < 4; ++i) av[i] = As[k][ty + i * 16];
#pragma unroll
      for (int j = 0; j < 8; ++j) bv[j] = Bs[k][tx + j * 16];
#pragma unroll
      for (int i = 0; i < 4; ++i)
#pragma unroll
        for (int j = 0; j < 8; ++j) acc[i][j] += av[i] * bv[j];
    }
    __syncthreads();
  }
#pragma unroll
  for (int i = 0; i < 4; ++i) {
    int m = m0 + ty + i * 16;
    float bs = bias ? bias[m] : 0.f;
#pragma unroll
    for (int j = 0; j < 8; ++j) {
      int n = n0 + tx + j * 16;
      float v = acc[i][j] + bs;
      if constexpr (ACT == 1) v = gelu_f(v);
      if constexpr (RESM == 1)
        v += ((const float*)res)[(size_t)((long long)z * resz) + (size_t)m * N + n];
      if constexpr (RESM == 2)
        v += cvt(((const bf16*)res)[(size_t)((long long)z * resz) + (size_t)m * N + n]);
      if constexpr (OUTM == 2)
        ((bf16*)out)[(size_t)((long long)z * outz) + (size_t)m * N + n] = __float2bfloat16(v);
      if constexpr (OUTM == 3)
        ((bf16*)out)[(size_t)((long long)z * outz) + (size_t)n * M + m] = __float2bfloat16(v);
      if constexpr (OUTM == 4)
        ((float*)out)[(size_t)((long long)z * outz) + (size_t)m * N + n] = v;
    }
  }
}

// ---------------- depthwise 3x3 stride-2 pad-1 conv (4,128,Hi,Wi) ----------
template<typename T>
__global__ __launch_bounds__(256) void dwconv_kernel(
    const T* __restrict__ in, const float* __restrict__ wgt,
    float* __restrict__ out, int Hi, int Wi, int Ho, int Wo, int fuse,
    const float* __restrict__ bg_, const float* __restrict__ bb_,
    const float* __restrict__ bm_, const float* __restrict__ bv_)
{
  int idx = blockIdx.x * 256 + threadIdx.x;
  int total = 4 * 128 * Ho * Wo;
  if (idx >= total) return;
  int ow = idx % Wo;
  int oh = (idx / Wo) % Ho;
  int c  = (idx / (Wo * Ho)) % 128;
  int bgi = idx / (Wo * Ho * 128);
  const T* ip = in + ((size_t)bgi * 128 + c) * Hi * Wi;
  float acc = 0.f;
#pragma unroll
  for (int ky = 0; ky < 3; ++ky) {
    int ih = oh * 2 - 1 + ky;
    if ((unsigned)ih >= (unsigned)Hi) continue;
#pragma unroll
    for (int kx = 0; kx < 3; ++kx) {
      int iw = ow * 2 - 1 + kx;
      if ((unsigned)iw >= (unsigned)Wi) continue;
      acc += wgt[c * 9 + ky * 3 + kx] * cvt(ip[ih * Wi + iw]);
    }
  }
  if (fuse) {
    acc = (acc - bm_[c]) * rsqrtf(bv_[c] + 1e-5f) * bg_[c] + bb_[c];
    acc = gelu_f(acc);
  }
  out[idx] = acc;
}

// ---------------- offset head: off4_w @ o -> tanh -> grid (pixel coords) ----
__global__ __launch_bounds__(256) void offgrid_kernel(
    const float* __restrict__ o, const float* __restrict__ w4,
    float* __restrict__ rows, float* __restrict__ cols)
{
  int idx = blockIdx.x * 256 + threadIdx.x;
  int nw = idx & 63;
  int r = (idx >> 6) & 1023;
  int coord = (idx >> 16) & 1;
  int bg = idx >> 17;
  const float* op = o + (size_t)bg * 8192 + nw;
  const float* wp = w4 + ((size_t)coord * 1024 + r) * 128;
  float acc = 0.f;
  for (int c = 0; c < 128; ++c) acc += wp[c] * op[c * 64];
  float val = tanhf(acc) * (2.0f / 64.0f);
  int rc = coord ? (r & 31) : (r >> 5);
  float ref = rc * (4.0f / 63.0f) - 1.0f;
  float pix = (val + ref + 1.0f) * 31.5f;
  (coord ? cols : rows)[(size_t)bg * 65536 + r * 64 + nw] = pix;
}

// ---------------- bilinear gather: kk/vv[b][nw][r][256] bf16 ----------------
// One block per (b, nw, rblk of 128 r). thread = (ch octet t&31, r-lane t>>5).
// kk[.. ,o] = k_b[o] + sum_g bilinear(Kimg[b,g], grid[b,g,r,nw])[o]; same vv.
__global__ __launch_bounds__(256) void gather_kernel(
    const unsigned short* __restrict__ Kimg, const unsigned short* __restrict__ Vimg,
    const float* __restrict__ rows_, const float* __restrict__ cols_,
    const float* __restrict__ kbv, const float* __restrict__ vbv,
    unsigned short* __restrict__ kk, unsigned short* __restrict__ vv)
{
  int t = threadIdx.x;
  int oct = t & 31, rloc = t >> 5;
  int rblk = blockIdx.x, nw = blockIdx.y, b = blockIdx.z;
  int ch = oct * 8;
  float kb0[8], vb0[8];
#pragma unroll
  for (int j = 0; j < 8; ++j) { kb0[j] = kbv[ch + j]; vb0[j] = vbv[ch + j]; }

  for (int i = 0; i < 16; ++i) {
    int r = rblk * 128 + i * 8 + rloc;
    float aK[8], aV[8];
#pragma unroll
    for (int j = 0; j < 8; ++j) { aK[j] = kb0[j]; aV[j] = vb0[j]; }
#pragma unroll
    for (int g = 0; g < 2; ++g) {
      int bg = b * 2 + g;
      float rowf = rows_[(size_t)bg * 65536 + r * 64 + nw];
      float colf = cols_[(size_t)bg * 65536 + r * 64 + nw];
      float r0f = floorf(rowf), c0f = floorf(colf);
      float wr = rowf - r0f, wc = colf - c0f;
      int r0 = (int)r0f, c0 = (int)c0f;
      bool rv0 = ((unsigned)r0 < 64u), rv1 = ((unsigned)(r0 + 1) < 64u);
      bool cv0 = ((unsigned)c0 < 64u), cv1 = ((unsigned)(c0 + 1) < 64u);
      float w00 = (rv0 && cv0) ? (1.f - wr) * (1.f - wc) : 0.f;
      float w01 = (rv0 && cv1) ? (1.f - wr) * wc : 0.f;
      float w10 = (rv1 && cv0) ? wr * (1.f - wc) : 0.f;
      float w11 = (rv1 && cv1) ? wr * wc : 0.f;
      int ra = min(max(r0, 0), 63), rb2 = min(max(r0 + 1, 0), 63);
      int ca = min(max(c0, 0), 63), cb2 = min(max(c0 + 1, 0), 63);
      size_t pb = (size_t)bg * 4096 * 256 + ch;
      size_t o00 = pb + (size_t)(ra * 64 + ca) * 256;
      size_t o01 = pb + (size_t)(ra * 64 + cb2) * 256;
      size_t o10 = pb + (size_t)(rb2 * 64 + ca) * 256;
      size_t o11 = pb + (size_t)(rb2 * 64 + cb2) * 256;
      U16x8 k00, k01, k10, k11, v00, v01, v10, v11;
      k00.u4 = *(const uint4*)(Kimg + o00); v00.u4 = *(const uint4*)(Vimg + o00);
      k01.u4 = *(const uint4*)(Kimg + o01); v01.u4 = *(const uint4*)(Vimg + o01);
      k10.u4 = *(const uint4*)(Kimg + o10); v10.u4 = *(const uint4*)(Vimg + o10);
      k11.u4 = *(const uint4*)(Kimg + o11); v11.u4 = *(const uint4*)(Vimg + o11);
#pragma unroll
      for (int j = 0; j < 8; ++j) {
        aK[j] += w00 * b2f(k00.us[j]) + w01 * b2f(k01.us[j])
               + w10 * b2f(k10.us[j]) + w11 * b2f(k11.us[j]);
        aV[j] += w00 * b2f(v00.us[j]) + w01 * b2f(v01.us[j])
               + w10 * b2f(v10.us[j]) + w11 * b2f(v11.us[j]);
      }
    }
    U16x8 ok, ov;
#pragma unroll
    for (int j = 0; j < 8; ++j) { ok.us[j] = f2b(aK[j]); ov.us[j] = f2b(aV[j]); }
    size_t dst = ((size_t)(b * 64 + nw) * 1024 + r) * 256 + ch;
    *(uint4*)(kk + dst) = ok.u4;
    *(uint4*)(vv + dst) = ov.u4;
  }
}

// ---------------- MFMA fused window attention -------------------------------
// One block per (b, head, nw); 4 waves; wave w owns q-rows [w*16, w*16+16).
// Online softmax over R=1024 in chunks of 64, state in registers.
// Layouts (verified m89/m91/m120): A[m=lane&15][k=quad*8+j],
// B[k=quad*8+j][n=lane&15], D col=lane&15 row=quad*4+reg.
__global__ __launch_bounds__(256) void attn_kernel(
    const bf16* __restrict__ qbuf, const unsigned short* __restrict__ kk,
    const unsigned short* __restrict__ vv, const float* __restrict__ pe,
    bf16* __restrict__ aout)
{
  __shared__ unsigned short qs[64][40];   // [q][hc] bf16, row 80B (16B mult)
  __shared__ unsigned short ks[64][40];   // [r][hc]
  __shared__ unsigned short vs[32][72];   // [hc][r] (transposed)
  __shared__ unsigned short Ps[64][72];   // [q][r] bf16
  __shared__ float pes[70][72];           // posembed window (f32)
  // LDS total = 5120+5120+4608+9216+20160 = 44,224 B -> 3 blocks/CU

  int blk = blockIdx.x;
  int nw = blk & 63, head = (blk >> 6) & 7, b = blk >> 9;
  int wh = nw >> 3, ww = nw & 7;
  int t = threadIdx.x;
  int lane = t & 63, w = t >> 6;
  int l15 = lane & 15, quad = lane >> 4;
  int qc0 = head * 32;

  // stage Q, scaled by C^-0.5 = 1/16
  {
    int hc = t >> 3, qrow = t & 7;
    const bf16* src = qbuf + ((size_t)b * 256 + qc0 + hc) * 4096
                      + (wh * 8 + qrow) * 64 + ww * 8;
    U16x8 u; u.u4 = *(const uint4*)src;
#pragma unroll
    for (int j = 0; j < 8; ++j)
      qs[qrow * 8 + j][hc] = f2b(b2f(u.us[j]) * 0.0625f);
  }
  // stage posembed sub-block
  int ry0 = 56 - wh * 8, rx0 = 56 - ww * 8;
  for (int i = t; i < 70 * 70; i += 256) {
    int yy = i / 70, xx = i % 70;
    pes[yy][xx] = pe[(size_t)head * 16129 + (ry0 + yy) * 127 + rx0 + xx];
  }
  __syncthreads();

  bf16x8 aQ;
  {
    uint4 u = *(const uint4*)&qs[w * 16 + l15][quad * 8];
    aQ = __builtin_bit_cast(bf16x8, u);
  }
  float m[4] = {-1e30f, -1e30f, -1e30f, -1e30f};
  float l[4] = {0.f, 0.f, 0.f, 0.f};
  f32x4 oacc[2];
  oacc[0] = (f32x4){0.f, 0.f, 0.f, 0.f};
  oacc[1] = (f32x4){0.f, 0.f, 0.f, 0.f};
  int qh[4], qw_[4];
#pragma unroll
  for (int reg = 0; reg < 4; ++reg) {
    int q = w * 16 + quad * 4 + reg;
    qh[reg] = q >> 3; qw_[reg] = q & 7;
  }
  size_t kvbase = ((size_t)(b * 64 + nw) * 1024) * 256 + qc0;

  for (int rc0 = 0; rc0 < 1024; rc0 += 64) {
    // stage K tile (coalesced 16B)
    {
      int r = t >> 2, seg = t & 3;
      *(uint4*)&ks[r][seg * 8] =
          *(const uint4*)(kk + kvbase + (size_t)(rc0 + r) * 256 + seg * 8);
    }
    // stage V tile transposed: vs[hc][r]
    {
      int hc = t & 31, rg = t >> 5;
      U16x8 u;
#pragma unroll
      for (int i2 = 0; i2 < 8; ++i2)
        u.us[i2] = vv[kvbase + (size_t)(rc0 + rg * 8 + i2) * 256 + hc];
      *(uint4*)&vs[hc][rg * 8] = u.u4;
    }
    __syncthreads();

    // S = Q.K^T via 4 MFMAs (ntiles over r)
    f32x4 s[4];
#pragma unroll
    for (int nt = 0; nt < 4; ++nt) {
      uint4 u = *(const uint4*)&ks[nt * 16 + l15][quad * 8];
      bf16x8 bK = __builtin_bit_cast(bf16x8, u);
      f32x4 z = (f32x4){0.f, 0.f, 0.f, 0.f};
      s[nt] = __builtin_amdgcn_mfma_f32_16x16x32_bf16(aQ, bK, z, 0, 0, 0);
    }
    // bias add from pes
#pragma unroll
    for (int nt = 0; nt < 4; ++nt) {
      int rg_ = nt * 16 + l15;
      int rrow = (rc0 + rg_) >> 5, rcol = rg_ & 31;
#pragma unroll
      for (int reg = 0; reg < 4; ++reg)
        s[nt][reg] += pes[2 * rrow + 7 - qh[reg]][2 * rcol + 7 - qw_[reg]];
    }
    // online softmax, state per q-row (quad-local)
    float alpha[4];
#pragma unroll
    for (int reg = 0; reg < 4; ++reg) {
      float mx = fmaxf(fmaxf(s[0][reg], s[1][reg]), fmaxf(s[2][reg], s[3][reg]));
      mx = fmaxf(mx, __shfl_xor(mx, 1, 64));
      mx = fmaxf(mx, __shfl_xor(mx, 2, 64));
      mx = fmaxf(mx, __shfl_xor(mx, 4, 64));
      mx = fmaxf(mx, __shfl_xor(mx, 8, 64));
      float mn = fmaxf(m[reg], mx);
      alpha[reg] = __expf(m[reg] - mn);
      m[reg] = mn;
      float ps = 0.f;
#pragma unroll
      for (int nt = 0; nt < 4; ++nt) {
        float p = __expf(s[nt][reg] - mn);
        Ps[w * 16 + quad * 4 + reg][nt * 16 + l15] = f2b(p);
        ps += p;
      }
      ps += __shfl_xor(ps, 1, 64);
      ps += __shfl_xor(ps, 2, 64);
      ps += __shfl_xor(ps, 4, 64);
      ps += __shfl_xor(ps, 8, 64);
      l[reg] = l[reg] * alpha[reg] + ps;
      oacc[0][reg] *= alpha[reg];
      oacc[1][reg] *= alpha[reg];
    }
    // O += P.V via 4 MFMAs (2 k-steps x 2 hc-tiles); Ps wave-local
#pragma unroll
    for (int kst = 0; kst < 2; ++kst) {
      uint4 up = *(const uint4*)&Ps[w * 16 + l15][kst * 32 + quad * 8];
      bf16x8 pA = __builtin_bit_cast(bf16x8, up);
#pragma unroll
      for (int nt2 = 0; nt2 < 2; ++nt2) {
        uint4 uv = *(const uint4*)&vs[nt2 * 16 + l15][kst * 32 + quad * 8];
        bf16x8 vB = __builtin_bit_cast(bf16x8, uv);
        oacc[nt2] = __builtin_amdgcn_mfma_f32_16x16x32_bf16(pA, vB, oacc[nt2], 0, 0, 0);
      }
    }
    __syncthreads();
  }
  // epilogue: divide by l, write scattered bf16
#pragma unroll
  for (int nt2 = 0; nt2 < 2; ++nt2) {
#pragma unroll
    for (int reg = 0; reg < 4; ++reg) {
      aout[((size_t)b * 256 + qc0 + nt2 * 16 + l15) * 4096
           + (wh * 8 + qh[reg]) * 64 + ww * 8 + qw_[reg]] =
          __float2bfloat16(oacc[nt2][reg] / l[reg]);
    }
  }
}

// ---------------------------------------------------------------------------
extern "C" void kernel_launch(void* const* d_in, const int* in_sizes, int n_in,
                              void* d_out, int out_size, void* d_ws, size_t ws_size,
                              hipStream_t stream) {
  (void)in_sizes; (void)n_in; (void)out_size; (void)ws_size;
  const float* x     = (const float*)d_in[0];
  const float* ln1g  = (const float*)d_in[1];
  const float* ln1b  = (const float*)d_in[2];
  const float* q_w   = (const float*)d_in[3];
  const float* q_b   = (const float*)d_in[4];
  const float* k_w   = (const float*)d_in[5];
  const float* k_b   = (const float*)d_in[6];
  const float* v_w   = (const float*)d_in[7];
  const float* v_b   = (const float*)d_in[8];
  const float* off1w = (const float*)d_in[9];
  const float* off2w = (const float*)d_in[10];
  const float* off3w = (const float*)d_in[11];
  const float* bng   = (const float*)d_in[12];
  const float* bnb   = (const float*)d_in[13];
  const float* bnm   = (const float*)d_in[14];
  const float* bnv   = (const float*)d_in[15];
  const float* off4w = (const float*)d_in[16];
  const float* pe    = (const float*)d_in[17];
  const float* pjw   = (const float*)d_in[18];
  const float* pjb   = (const float*)d_in[19];
  const float* ln2g  = (const float*)d_in[20];
  const float* ln2b  = (const float*)d_in[21];
  const float* w1    = (const float*)d_in[22];
  const float* b1    = (const float*)d_in[23];
  const float* w2    = (const float*)d_in[24];
  const float* b2    = (const float*)d_in[25];
  float* outp = (float*)d_out;

  // workspace arena (~161 MB), all offsets 16B-aligned
  char* W = (char*)d_ws;
  bf16*  xa   = (bf16*) (W + 0);          // 4MB  LN1 out; reused as aout
  bf16*  qb   = (bf16*) (W + 4194304);    // 4MB  q; reused as xm
  float* dw1  = (float*)(W + 8388608);    // 2MB
  float* dw2  = (float*)(W + 10485760);   // 512KB
  float* dw3  = (float*)(W + 11010048);   // 128KB
  float* rows = (float*)(W + 11141120);   // 1MB
  float* cols = (float*)(W + 12189696);   // 1MB
  bf16*  Kimg = (bf16*) (W + 13238272);   // 8MB (bg,hw,o) pixel-major
  bf16*  Vimg = (bf16*) (W + 21626880);   // 8MB
  bf16*  x2   = (bf16*) (W + 30015488);   // 4MB
  unsigned short* kkb = (unsigned short*)(W + 34209792);   // 64MB kk
  unsigned short* vvb = (unsigned short*)(W + 101318656);  // 64MB vv
  bf16*  aout = xa;                       // xa dead after Kimg/Vimg GEMMs
  bf16*  xm   = qb;                       // q dead after attention
  bf16*  hdn  = (bf16*)kkb;               // kk dead after attention (16MB need)

  // 1. LN1
  ln_kernel<float><<<256, 256, 0, stream>>>(x, ln1g, ln1b, xa);
  // 2. q = q_w @ xa + q_b
  gemm_kernel<2, 0, 0><<<dim3(32, 4, 2), 256, 0, stream>>>(
      q_w, xa, q_b, nullptr, qb, 256, 4096, 256, 256, 1048576LL, 0LL, 1048576LL);
  // 3. offset branch
  dwconv_kernel<bf16><<<2048, 256, 0, stream>>>(qb, off1w, dw1, 64, 64, 32, 32, 0,
                                                nullptr, nullptr, nullptr, nullptr);
  dwconv_kernel<float><<<512, 256, 0, stream>>>(dw1, off2w, dw2, 32, 32, 16, 16, 0,
                                                nullptr, nullptr, nullptr, nullptr);
  dwconv_kernel<float><<<128, 256, 0, stream>>>(dw2, off3w, dw3, 16, 16, 8, 8, 1,
                                                bng, bnb, bnm, bnv);
  // 4. sampling grid
  offgrid_kernel<<<2048, 256, 0, stream>>>(dw3, off4w, rows, cols);
  // 5. Kimg/Vimg pixel-major
  gemm_kernel<3, 0, 0><<<dim3(32, 4, 2), 256, 0, stream>>>(
      k_w,       xa,          nullptr, nullptr, Kimg,           256, 4096, 128, 256, 1048576LL, 0LL, 2097152LL);
  gemm_kernel<3, 0, 0><<<dim3(32, 4, 2), 256, 0, stream>>>(
      k_w + 128, xa + 524288, nullptr, nullptr, Kimg + 1048576, 256, 4096, 128, 256, 1048576LL, 0LL, 2097152LL);
  gemm_kernel<3, 0, 0><<<dim3(32, 4, 2), 256, 0, stream>>>(
      v_w,       xa,          nullptr, nullptr, Vimg,           256, 4096, 128, 256, 1048576LL, 0LL, 2097152LL);
  gemm_kernel<3, 0, 0><<<dim3(32, 4, 2), 256, 0, stream>>>(
      v_w + 128, xa + 524288, nullptr, nullptr, Vimg + 1048576, 256, 4096, 128, 256, 1048576LL, 0LL, 2097152LL);
  // 6. bilinear gather -> kk/vv  (once, shared by all heads)
  gather_kernel<<<dim3(8, 64, 2), 256, 0, stream>>>(
      (const unsigned short*)Kimg, (const unsigned short*)Vimg,
      rows, cols, k_b, v_b, kkb, vvb);
  // 7. MFMA fused attention (writes aout = xa)
  attn_kernel<<<1024, 256, 0, stream>>>(qb, kkb, vvb, pe, aout);
  // 8. proj + residual(x) -> x2
  gemm_kernel<2, 1, 0><<<dim3(32, 4, 2), 256, 0, stream>>>(
      pjw, aout, pjb, (const void*)x, x2, 256, 4096, 256, 256, 1048576LL, 1048576LL, 1048576LL);
  // 9. LN2
  ln_kernel<bf16><<<256, 256, 0, stream>>>(x2, ln2g, ln2b, xm);
  // 10. MLP1 + GELU
  gemm_kernel<2, 0, 1><<<dim3(32, 16, 2), 256, 0, stream>>>(
      w1, xm, b1, nullptr, hdn, 1024, 4096, 256, 256, 1048576LL, 0LL, 4194304LL);
  // 11. MLP2 + residual(x2) -> f32 d_out
  gemm_kernel<4, 2, 0><<<dim3(32, 4, 2), 256, 0, stream>>>(
      w2, hdn, b2, (const void*)x2, outp, 256, 4096, 1024, 1024, 4194304LL, 1048576LL, 1048576LL);
}

// Round 5
// 469.048 us; speedup vs baseline: 2.9214x; 1.7322x over previous
//
#include <hip/hip_runtime.h>
#include <hip/hip_bf16.h>
#include <math.h>

// CBiAFormerBlock fused implementation, round 5.
// Change vs r4 (PASS, 812us): entire pipeline flipped to pixel-major (NHWC)
// so every 1x1-conv GEMM runs on MFMA with BOTH operands natural row-major:
// out[p][o] = sum_c act[p][c] * w[o][c]  (A-frag = act rows, B-frag = weight
// rows; operand orientation HW-validated by r4's attn kernel). New
// mgemm_kernel: 128x128 tile, BK=64, 4 waves x 64x64, 16 MFMA per 8
// ds_read_b128 (LDS/MFMA balanced), f32 weights -> bf16 during staging.
// M=8192 folds both batches. LN/dwconv/offgrid/gather/attn re-indexed NHWC.

typedef __hip_bfloat16 bf16;
typedef __bf16 bf16x8 __attribute__((ext_vector_type(8)));
typedef float f32x4 __attribute__((ext_vector_type(4)));

union U16x8 { uint4 u4; unsigned short us[8]; };

__device__ __forceinline__ float cvt(float x) { return x; }
__device__ __forceinline__ float cvt(bf16 x) { return __bfloat162float(x); }
__device__ __forceinline__ float b2f(unsigned short u) {
  union { float f; unsigned int v; } x; x.v = ((unsigned int)u) << 16; return x.f;
}
__device__ __forceinline__ unsigned short f2b(float f) {
  bf16 h = __float2bfloat16(f);
  return *reinterpret_cast<unsigned short*>(&h);
}
__device__ __forceinline__ float gelu_f(float x) {
  return 0.5f * x * (1.0f + erff(x * 0.7071067811865475f));
}

// ---------------- LN1: NCHW f32 in -> NHWC bf16 out ------------------------
// 32 pixels/block; coalesced NCHW reads, LDS transpose, uint4 NHWC writes.
__global__ __launch_bounds__(256) void ln1_kernel(
    const float* __restrict__ x, const float* __restrict__ g,
    const float* __restrict__ bta, bf16* __restrict__ out)
{
  __shared__ float s1[8][32], s2[8][32];
  __shared__ unsigned short tb[32][264];
  int t = threadIdx.x;
  int pos = t & 31, cs = t >> 5;
  int p = blockIdx.x * 32 + pos;
  int bb = p >> 12, hw = p & 4095;
  const float* xp = x + (size_t)bb * 256 * 4096 + hw;
  float vloc[32];
  float sum = 0.f, ss = 0.f;
#pragma unroll
  for (int i = 0; i < 32; ++i) {
    float v = xp[(size_t)(cs * 32 + i) * 4096];
    vloc[i] = v; sum += v; ss += v * v;
  }
  s1[cs][pos] = sum; s2[cs][pos] = ss;
  __syncthreads();
  if (cs == 0) {
    float S = 0.f, Q = 0.f;
#pragma unroll
    for (int i = 0; i < 8; ++i) { S += s1[i][pos]; Q += s2[i][pos]; }
    float mu = S * (1.f / 256.f);
    float var = Q * (1.f / 256.f) - mu * mu;
    s1[0][pos] = mu;
    s2[0][pos] = rsqrtf(var + 1e-5f);
  }
  __syncthreads();
  float mu = s1[0][pos], rs = s2[0][pos];
#pragma unroll
  for (int i = 0; i < 32; ++i) {
    int c = cs * 32 + i;
    tb[pos][c] = f2b((vloc[i] - mu) * rs * g[c] + bta[c]);
  }
  __syncthreads();
  int px = t >> 3, grp = t & 7;
  bf16* op = out + ((size_t)blockIdx.x * 32 + px) * 256 + grp * 32;
#pragma unroll
  for (int q = 0; q < 4; ++q)
    *(uint4*)(op + q * 8) = *(const uint4*)&tb[px][grp * 32 + q * 8];
}

// ---------------- LN2: NHWC bf16 in -> NHWC bf16 out -----------------------
__global__ __launch_bounds__(256) void ln2_kernel(
    const bf16* __restrict__ xin, const float* __restrict__ g,
    const float* __restrict__ bta, bf16* __restrict__ out)
{
  __shared__ float sa[8][32], sb[8][32];
  __shared__ float mu_s[32], rs_s[32];
  int t = threadIdx.x;
  int px = t >> 3, grp = t & 7;
  size_t p = (size_t)blockIdx.x * 32 + px;
  const bf16* xp = xin + p * 256 + grp * 32;
  float v[32]; float sum = 0.f, ss = 0.f;
#pragma unroll
  for (int q = 0; q < 4; ++q) {
    U16x8 u; u.u4 = *(const uint4*)(xp + q * 8);
#pragma unroll
    for (int j = 0; j < 8; ++j) {
      float f = b2f(u.us[j]); v[q * 8 + j] = f; sum += f; ss += f * f;
    }
  }
  sa[grp][px] = sum; sb[grp][px] = ss;
  __syncthreads();
  if (t < 32) {
    float S = 0.f, Q = 0.f;
#pragma unroll
    for (int i = 0; i < 8; ++i) { S += sa[i][t]; Q += sb[i][t]; }
    float mu = S * (1.f / 256.f);
    mu_s[t] = mu;
    rs_s[t] = rsqrtf(Q * (1.f / 256.f) - mu * mu + 1e-5f);
  }
  __syncthreads();
  float mu = mu_s[px], rs = rs_s[px];
  bf16* op = out + p * 256 + grp * 32;
#pragma unroll
  for (int q = 0; q < 4; ++q) {
    U16x8 o;
#pragma unroll
    for (int j = 0; j < 8; ++j) {
      int c = grp * 32 + q * 8 + j;
      o.us[j] = f2b((v[q * 8 + j] - mu) * rs * g[c] + bta[c]);
    }
    *(uint4*)(op + q * 8) = o.u4;
  }
}

// ---------------- MFMA GEMM (NHWC): out[p][o] = sum_c A[p][c] W[o][c] ------
// M=8192 (grid.y=64, BM=128), BN=128 (grid.x=N/128), BK=64.
// 4 waves as 2x2, each 64x64 via 4x4 grid of 16x16x32 MFMAs.
// OUTM: 0 = bf16 NHWC [m*N+n], 1 = f32 NCHW scatter.
// RESM: 0 none, 1 f32 NCHW (input x), 2 bf16 NHWC. ACT: 1 = exact GELU.
template<int OUTM, int RESM, int ACT>
__global__ __launch_bounds__(256) void mgemm_kernel(
    const bf16* __restrict__ A, const float* __restrict__ Bw,
    const float* __restrict__ bias, const void* __restrict__ res,
    void* __restrict__ out, int N, int K, int lda, int ldb)
{
  constexpr int BK = 64;
  __shared__ unsigned short As[128][BK + 8];   // 18432 B
  __shared__ unsigned short Bs[128][BK + 8];   // 18432 B
  int t = threadIdx.x;
  int m0 = blockIdx.y * 128, n0 = blockIdx.x * 128;
  int lane = t & 63, w = t >> 6;
  int l15 = lane & 15, quad = lane >> 4;
  int wm = (w >> 1) * 64, wn = (w & 1) * 64;
  f32x4 acc[4][4];
#pragma unroll
  for (int mt = 0; mt < 4; ++mt)
#pragma unroll
    for (int nt = 0; nt < 4; ++nt) acc[mt][nt] = (f32x4){0.f, 0.f, 0.f, 0.f};

  for (int k0 = 0; k0 < K; k0 += BK) {
    // stage A (bf16 NHWC activations): 128 rows x 64 k
#pragma unroll
    for (int i = 0; i < 4; ++i) {
      int idx = t + i * 256;
      int m = idx >> 3, oc = (idx & 7) * 8;
      *(uint4*)&As[m][oc] = *(const uint4*)(A + (size_t)(m0 + m) * lda + k0 + oc);
    }
    // stage B (f32 weights -> bf16): 128 rows x 64 k
    {
      int n = t >> 1, h = (t & 1) * 32;
      const float* bp = Bw + (size_t)(n0 + n) * ldb + k0 + h;
#pragma unroll
      for (int q = 0; q < 2; ++q) {
        float4 f0 = *(const float4*)(bp + q * 16);
        float4 f1 = *(const float4*)(bp + q * 16 + 4);
        float4 f2 = *(const float4*)(bp + q * 16 + 8);
        float4 f3 = *(const float4*)(bp + q * 16 + 12);
        U16x8 u0, u1;
        u0.us[0] = f2b(f0.x); u0.us[1] = f2b(f0.y); u0.us[2] = f2b(f0.z); u0.us[3] = f2b(f0.w);
        u0.us[4] = f2b(f1.x); u0.us[5] = f2b(f1.y); u0.us[6] = f2b(f1.z); u0.us[7] = f2b(f1.w);
        u1.us[0] = f2b(f2.x); u1.us[1] = f2b(f2.y); u1.us[2] = f2b(f2.z); u1.us[3] = f2b(f2.w);
        u1.us[4] = f2b(f3.x); u1.us[5] = f2b(f3.y); u1.us[6] = f2b(f3.z); u1.us[7] = f2b(f3.w);
        *(uint4*)&Bs[n][h + q * 16] = u0.u4;
        *(uint4*)&Bs[n][h + q * 16 + 8] = u1.u4;
      }
    }
    __syncthreads();
#pragma unroll
    for (int ks = 0; ks < 2; ++ks) {
      bf16x8 af[4], bfr[4];
#pragma unroll
      for (int mt = 0; mt < 4; ++mt)
        af[mt] = __builtin_bit_cast(bf16x8,
            *(const uint4*)&As[wm + mt * 16 + l15][ks * 32 + quad * 8]);
#pragma unroll
      for (int nt = 0; nt < 4; ++nt)
        bfr[nt] = __builtin_bit_cast(bf16x8,
            *(const uint4*)&Bs[wn + nt * 16 + l15][ks * 32 + quad * 8]);
#pragma unroll
      for (int mt = 0; mt < 4; ++mt)
#pragma unroll
        for (int nt = 0; nt < 4; ++nt)
          acc[mt][nt] = __builtin_amdgcn_mfma_f32_16x16x32_bf16(
              af[mt], bfr[nt], acc[mt][nt], 0, 0, 0);
    }
    __syncthreads();
  }
  // epilogue: D col = l15 (n), row = quad*4+reg (m)
  float bv[4];
#pragma unroll
  for (int nt = 0; nt < 4; ++nt)
    bv[nt] = bias ? bias[n0 + wn + nt * 16 + l15] : 0.f;
#pragma unroll
  for (int mt = 0; mt < 4; ++mt) {
#pragma unroll
    for (int nt = 0; nt < 4; ++nt) {
#pragma unroll
      for (int reg = 0; reg < 4; ++reg) {
        int m = m0 + wm + mt * 16 + quad * 4 + reg;
        int n = n0 + wn + nt * 16 + l15;
        float v = acc[mt][nt][reg] + bv[nt];
        if constexpr (ACT == 1) v = gelu_f(v);
        if constexpr (RESM == 1)
          v += ((const float*)res)[((size_t)(m >> 12) * 256 + n) * 4096 + (m & 4095)];
        if constexpr (RESM == 2)
          v += b2f(((const unsigned short*)res)[(size_t)m * 256 + n]);
        if constexpr (OUTM == 0)
          ((unsigned short*)out)[(size_t)m * N + n] = f2b(v);
        else
          ((float*)out)[((size_t)(m >> 12) * 256 + n) * 4096 + (m & 4095)] = v;
      }
    }
  }
}

// ---------------- depthwise 3x3 stride-2 pad-1 conv, NHWC-128 --------------
// IC=256: input qb NHWC-256, group channels g*128+c. IC=128: dw intermediates.
template<typename T, int IC>
__global__ __launch_bounds__(256) void dwconv_kernel(
    const T* __restrict__ in, const float* __restrict__ wgt,
    float* __restrict__ out, int Hi, int Wi, int Ho, int Wo, int fuse,
    const float* __restrict__ bg_, const float* __restrict__ bb_,
    const float* __restrict__ bm_, const float* __restrict__ bv_)
{
  int idx = blockIdx.x * 256 + threadIdx.x;
  int c = idx & 127;
  int pp = idx >> 7;
  int ow = pp % Wo, oh = (pp / Wo) % Ho, bgi = pp / (Wo * Ho);
  const T* ip;
  if constexpr (IC == 256)
    ip = in + ((size_t)(bgi >> 1) * 4096) * 256 + (bgi & 1) * 128 + c;
  else
    ip = in + ((size_t)bgi * Hi * Wi) * 128 + c;
  float acc = 0.f;
#pragma unroll
  for (int ky = 0; ky < 3; ++ky) {
    int ih = oh * 2 - 1 + ky;
    if ((unsigned)ih >= (unsigned)Hi) continue;
#pragma unroll
    for (int kx = 0; kx < 3; ++kx) {
      int iw = ow * 2 - 1 + kx;
      if ((unsigned)iw >= (unsigned)Wi) continue;
      acc += wgt[c * 9 + ky * 3 + kx] * cvt(ip[(size_t)(ih * Wi + iw) * IC]);
    }
  }
  if (fuse) {
    acc = (acc - bm_[c]) * rsqrtf(bv_[c] + 1e-5f) * bg_[c] + bb_[c];
    acc = gelu_f(acc);
  }
  out[idx] = acc;
}

// ---------------- offset head: off4_w @ o -> tanh -> grid (pixel coords) ----
// dw3 is NHWC-128 [bg][64px][128c]; both dot operands contiguous.
__global__ __launch_bounds__(256) void offgrid_kernel(
    const float* __restrict__ o, const float* __restrict__ w4,
    float* __restrict__ rows, float* __restrict__ cols)
{
  int idx = blockIdx.x * 256 + threadIdx.x;
  int nw = idx & 63;
  int r = (idx >> 6) & 1023;
  int coord = (idx >> 16) & 1;
  int bg = idx >> 17;
  const float* op = o + ((size_t)bg * 64 + nw) * 128;
  const float* wp = w4 + ((size_t)coord * 1024 + r) * 128;
  float acc = 0.f;
  for (int c = 0; c < 128; ++c) acc += wp[c] * op[c];
  float val = tanhf(acc) * (2.0f / 64.0f);
  int rc = coord ? (r & 31) : (r >> 5);
  float ref = rc * (4.0f / 63.0f) - 1.0f;
  float pix = (val + ref + 1.0f) * 31.5f;
  (coord ? cols : rows)[(size_t)bg * 65536 + r * 64 + nw] = pix;
}

// ---------------- bilinear gather: kk/vv[b][nw][r][256] bf16 ----------------
// Kimg/Vimg layout [g][b*4096+hw][256] bf16 (NHWC, group-major).
__global__ __launch_bounds__(256) void gather_kernel(
    const unsigned short* __restrict__ Kimg, const unsigned short* __restrict__ Vimg,
    const float* __restrict__ rows_, const float* __restrict__ cols_,
    const float* __restrict__ kbv, const float* __restrict__ vbv,
    unsigned short* __restrict__ kk, unsigned short* __restrict__ vv)
{
  int t = threadIdx.x;
  int oct = t & 31, rloc = t >> 5;
  int rblk = blockIdx.x, nw = blockIdx.y, b = blockIdx.z;
  int ch = oct * 8;
  float kb0[8], vb0[8];
#pragma unroll
  for (int j = 0; j < 8; ++j) { kb0[j] = kbv[ch + j]; vb0[j] = vbv[ch + j]; }

  for (int i = 0; i < 16; ++i) {
    int r = rblk * 128 + i * 8 + rloc;
    float aK[8], aV[8];
#pragma unroll
    for (int j = 0; j < 8; ++j) { aK[j] = kb0[j]; aV[j] = vb0[j]; }
#pragma unroll
    for (int g = 0; g < 2; ++g) {
      int bg = b * 2 + g;
      float rowf = rows_[(size_t)bg * 65536 + r * 64 + nw];
      float colf = cols_[(size_t)bg * 65536 + r * 64 + nw];
      float r0f = floorf(rowf), c0f = floorf(colf);
      float wr = rowf - r0f, wc = colf - c0f;
      int r0 = (int)r0f, c0 = (int)c0f;
      bool rv0 = ((unsigned)r0 < 64u), rv1 = ((unsigned)(r0 + 1) < 64u);
      bool cv0 = ((unsigned)c0 < 64u), cv1 = ((unsigned)(c0 + 1) < 64u);
      float w00 = (rv0 && cv0) ? (1.f - wr) * (1.f - wc) : 0.f;
      float w01 = (rv0 && cv1) ? (1.f - wr) * wc : 0.f;
      float w10 = (rv1 && cv0) ? wr * (1.f - wc) : 0.f;
      float w11 = (rv1 && cv1) ? wr * wc : 0.f;
      int ra = min(max(r0, 0), 63), rb2 = min(max(r0 + 1, 0), 63);
      int ca = min(max(c0, 0), 63), cb2 = min(max(c0 + 1, 0), 63);
      size_t pb = ((size_t)g * 8192 + (size_t)b * 4096) * 256 + ch;
      size_t o00 = pb + (size_t)(ra * 64 + ca) * 256;
      size_t o01 = pb + (size_t)(ra * 64 + cb2) * 256;
      size_t o10 = pb + (size_t)(rb2 * 64 + ca) * 256;
      size_t o11 = pb + (size_t)(rb2 * 64 + cb2) * 256;
      U16x8 k00, k01, k10, k11, v00, v01, v10, v11;
      k00.u4 = *(const uint4*)(Kimg + o00); v00.u4 = *(const uint4*)(Vimg + o00);
      k01.u4 = *(const uint4*)(Kimg + o01); v01.u4 = *(const uint4*)(Vimg + o01);
      k10.u4 = *(const uint4*)(Kimg + o10); v10.u4 = *(const uint4*)(Vimg + o10);
      k11.u4 = *(const uint4*)(Kimg + o11); v11.u4 = *(const uint4*)(Vimg + o11);
#pragma unroll
      for (int j = 0; j < 8; ++j) {
        aK[j] += w00 * b2f(k00.us[j]) + w01 * b2f(k01.us[j])
               + w10 * b2f(k10.us[j]) + w11 * b2f(k11.us[j]);
        aV[j] += w00 * b2f(v00.us[j]) + w01 * b2f(v01.us[j])
               + w10 * b2f(v10.us[j]) + w11 * b2f(v11.us[j]);
      }
    }
    U16x8 ok, ov;
#pragma unroll
    for (int j = 0; j < 8; ++j) { ok.us[j] = f2b(aK[j]); ov.us[j] = f2b(aV[j]); }
    size_t dst = ((size_t)(b * 64 + nw) * 1024 + r) * 256 + ch;
    *(uint4*)(kk + dst) = ok.u4;
    *(uint4*)(vv + dst) = ov.u4;
  }
}

// ---------------- MFMA fused window attention (NHWC q / aout) --------------
__global__ __launch_bounds__(256) void attn_kernel(
    const bf16* __restrict__ qbuf, const unsigned short* __restrict__ kk,
    const unsigned short* __restrict__ vv, const float* __restrict__ pe,
    bf16* __restrict__ aout)
{
  __shared__ unsigned short qs[64][40];
  __shared__ unsigned short ks[64][40];
  __shared__ unsigned short vs[32][72];
  __shared__ unsigned short Ps[64][72];
  __shared__ float pes[70][72];

  int blk = blockIdx.x;
  int nw = blk & 63, head = (blk >> 6) & 7, b = blk >> 9;
  int wh = nw >> 3, ww = nw & 7;
  int t = threadIdx.x;
  int lane = t & 63, w = t >> 6;
  int l15 = lane & 15, quad = lane >> 4;
  int qc0 = head * 32;

  // stage Q from NHWC, scaled by C^-0.5 = 1/16
  {
    int qt = t >> 2, oct = t & 3;
    int h = wh * 8 + (qt >> 3), wcol = ww * 8 + (qt & 7);
    const bf16* src = qbuf + ((size_t)b * 4096 + h * 64 + wcol) * 256 + qc0 + oct * 8;
    U16x8 u; u.u4 = *(const uint4*)src;
    U16x8 o;
#pragma unroll
    for (int j = 0; j < 8; ++j) o.us[j] = f2b(b2f(u.us[j]) * 0.0625f);
    *(uint4*)&qs[qt][oct * 8] = o.u4;
  }
  int ry0 = 56 - wh * 8, rx0 = 56 - ww * 8;
  for (int i = t; i < 70 * 70; i += 256) {
    int yy = i / 70, xx = i % 70;
    pes[yy][xx] = pe[(size_t)head * 16129 + (ry0 + yy) * 127 + rx0 + xx];
  }
  __syncthreads();

  bf16x8 aQ;
  {
    uint4 u = *(const uint4*)&qs[w * 16 + l15][quad * 8];
    aQ = __builtin_bit_cast(bf16x8, u);
  }
  float m[4] = {-1e30f, -1e30f, -1e30f, -1e30f};
  float l[4] = {0.f, 0.f, 0.f, 0.f};
  f32x4 oacc[2];
  oacc[0] = (f32x4){0.f, 0.f, 0.f, 0.f};
  oacc[1] = (f32x4){0.f, 0.f, 0.f, 0.f};
  int qh[4], qw_[4];
#pragma unroll
  for (int reg = 0; reg < 4; ++reg) {
    int q = w * 16 + quad * 4 + reg;
    qh[reg] = q >> 3; qw_[reg] = q & 7;
  }
  size_t kvbase = ((size_t)(b * 64 + nw) * 1024) * 256 + qc0;

  for (int rc0 = 0; rc0 < 1024; rc0 += 64) {
    {
      int r = t >> 2, seg = t & 3;
      *(uint4*)&ks[r][seg * 8] =
          *(const uint4*)(kk + kvbase + (size_t)(rc0 + r) * 256 + seg * 8);
    }
    {
      int hc = t & 31, rg = t >> 5;
      U16x8 u;
#pragma unroll
      for (int i2 = 0; i2 < 8; ++i2)
        u.us[i2] = vv[kvbase + (size_t)(rc0 + rg * 8 + i2) * 256 + hc];
      *(uint4*)&vs[hc][rg * 8] = u.u4;
    }
    __syncthreads();

    f32x4 s[4];
#pragma unroll
    for (int nt = 0; nt < 4; ++nt) {
      uint4 u = *(const uint4*)&ks[nt * 16 + l15][quad * 8];
      bf16x8 bK = __builtin_bit_cast(bf16x8, u);
      f32x4 z = (f32x4){0.f, 0.f, 0.f, 0.f};
      s[nt] = __builtin_amdgcn_mfma_f32_16x16x32_bf16(aQ, bK, z, 0, 0, 0);
    }
#pragma unroll
    for (int nt = 0; nt < 4; ++nt) {
      int rg_ = nt * 16 + l15;
      int rrow = (rc0 + rg_) >> 5, rcol = rg_ & 31;
#pragma unroll
      for (int reg = 0; reg < 4; ++reg)
        s[nt][reg] += pes[2 * rrow + 7 - qh[reg]][2 * rcol + 7 - qw_[reg]];
    }
    float alpha[4];
#pragma unroll
    for (int reg = 0; reg < 4; ++reg) {
      float mx = fmaxf(fmaxf(s[0][reg], s[1][reg]), fmaxf(s[2][reg], s[3][reg]));
      mx = fmaxf(mx, __shfl_xor(mx, 1, 64));
      mx = fmaxf(mx, __shfl_xor(mx, 2, 64));
      mx = fmaxf(mx, __shfl_xor(mx, 4, 64));
      mx = fmaxf(mx, __shfl_xor(mx, 8, 64));
      float mn = fmaxf(m[reg], mx);
      alpha[reg] = __expf(m[reg] - mn);
      m[reg] = mn;
      float ps = 0.f;
#pragma unroll
      for (int nt = 0; nt < 4; ++nt) {
        float p = __expf(s[nt][reg] - mn);
        Ps[w * 16 + quad * 4 + reg][nt * 16 + l15] = f2b(p);
        ps += p;
      }
      ps += __shfl_xor(ps, 1, 64);
      ps += __shfl_xor(ps, 2, 64);
      ps += __shfl_xor(ps, 4, 64);
      ps += __shfl_xor(ps, 8, 64);
      l[reg] = l[reg] * alpha[reg] + ps;
      oacc[0][reg] *= alpha[reg];
      oacc[1][reg] *= alpha[reg];
    }
#pragma unroll
    for (int kst = 0; kst < 2; ++kst) {
      uint4 up = *(const uint4*)&Ps[w * 16 + l15][kst * 32 + quad * 8];
      bf16x8 pA = __builtin_bit_cast(bf16x8, up);
#pragma unroll
      for (int nt2 = 0; nt2 < 2; ++nt2) {
        uint4 uv = *(const uint4*)&vs[nt2 * 16 + l15][kst * 32 + quad * 8];
        bf16x8 vB = __builtin_bit_cast(bf16x8, uv);
        oacc[nt2] = __builtin_amdgcn_mfma_f32_16x16x32_bf16(pA, vB, oacc[nt2], 0, 0, 0);
      }
    }
    __syncthreads();
  }
  // epilogue: NHWC writes
#pragma unroll
  for (int nt2 = 0; nt2 < 2; ++nt2) {
#pragma unroll
    for (int reg = 0; reg < 4; ++reg) {
      size_t p = (size_t)b * 4096 + (wh * 8 + qh[reg]) * 64 + ww * 8 + qw_[reg];
      aout[p * 256 + qc0 + nt2 * 16 + l15] =
          __float2bfloat16(oacc[nt2][reg] / l[reg]);
    }
  }
}

// ---------------------------------------------------------------------------
extern "C" void kernel_launch(void* const* d_in, const int* in_sizes, int n_in,
                              void* d_out, int out_size, void* d_ws, size_t ws_size,
                              hipStream_t stream) {
  (void)in_sizes; (void)n_in; (void)out_size; (void)ws_size;
  const float* x     = (const float*)d_in[0];
  const float* ln1g  = (const float*)d_in[1];
  const float* ln1b  = (const float*)d_in[2];
  const float* q_w   = (const float*)d_in[3];
  const float* q_b   = (const float*)d_in[4];
  const float* k_w   = (const float*)d_in[5];
  const float* k_b   = (const float*)d_in[6];
  const float* v_w   = (const float*)d_in[7];
  const float* v_b   = (const float*)d_in[8];
  const float* off1w = (const float*)d_in[9];
  const float* off2w = (const float*)d_in[10];
  const float* off3w = (const float*)d_in[11];
  const float* bng   = (const float*)d_in[12];
  const float* bnb   = (const float*)d_in[13];
  const float* bnm   = (const float*)d_in[14];
  const float* bnv   = (const float*)d_in[15];
  const float* off4w = (const float*)d_in[16];
  const float* pe    = (const float*)d_in[17];
  const float* pjw   = (const float*)d_in[18];
  const float* pjb   = (const float*)d_in[19];
  const float* ln2g  = (const float*)d_in[20];
  const float* ln2b  = (const float*)d_in[21];
  const float* w1    = (const float*)d_in[22];
  const float* b1    = (const float*)d_in[23];
  const float* w2    = (const float*)d_in[24];
  const float* b2    = (const float*)d_in[25];
  float* outp = (float*)d_out;

  // workspace arena (~165 MB), all offsets 16B-aligned; all act buffers NHWC
  char* W = (char*)d_ws;
  bf16*  xa   = (bf16*) (W + 0);          // [8192][256] bf16; reused as aout
  bf16*  qb   = (bf16*) (W + 4194304);    // [8192][256]; reused as xm
  float* dw1  = (float*)(W + 8388608);    // [4][1024][128] f32
  float* dw2  = (float*)(W + 10485760);   // [4][256][128]
  float* dw3  = (float*)(W + 11010048);   // [4][64][128]
  float* rows = (float*)(W + 11141120);   // 1MB
  float* cols = (float*)(W + 12189696);   // 1MB
  bf16*  Kimg = (bf16*) (W + 13238272);   // [2g][8192][256] bf16
  bf16*  Vimg = (bf16*) (W + 21626880);   // [2g][8192][256]
  bf16*  x2   = (bf16*) (W + 30015488);   // [8192][256]
  unsigned short* kkb = (unsigned short*)(W + 34209792);   // 64MB
  unsigned short* vvb = (unsigned short*)(W + 101318656);  // 64MB
  bf16*  aout = xa;
  bf16*  xm   = qb;
  bf16*  hdn  = (bf16*)kkb;               // [8192][1024] bf16 over kk (dead)

  // 1. LN1 (NCHW f32 -> NHWC bf16)
  ln1_kernel<<<256, 256, 0, stream>>>(x, ln1g, ln1b, xa);
  // 2. q = xa @ q_w^T + q_b  (NHWC)
  mgemm_kernel<0, 0, 0><<<dim3(2, 64), 256, 0, stream>>>(
      xa, q_w, q_b, nullptr, qb, 256, 256, 256, 256);
  // 3. offset branch (NHWC-128)
  dwconv_kernel<bf16, 256><<<2048, 256, 0, stream>>>(qb, off1w, dw1, 64, 64, 32, 32, 0,
                                                     nullptr, nullptr, nullptr, nullptr);
  dwconv_kernel<float, 128><<<512, 256, 0, stream>>>(dw1, off2w, dw2, 32, 32, 16, 16, 0,
                                                     nullptr, nullptr, nullptr, nullptr);
  dwconv_kernel<float, 128><<<128, 256, 0, stream>>>(dw2, off3w, dw3, 16, 16, 8, 8, 1,
                                                     bng, bnb, bnm, bnv);
  // 4. sampling grid
  offgrid_kernel<<<2048, 256, 0, stream>>>(dw3, off4w, rows, cols);
  // 5. Kimg/Vimg per group (full 256 out-ch, 128-ch K slice)
  mgemm_kernel<0, 0, 0><<<dim3(2, 64), 256, 0, stream>>>(
      xa,       k_w,       nullptr, nullptr, Kimg,           256, 128, 256, 256);
  mgemm_kernel<0, 0, 0><<<dim3(2, 64), 256, 0, stream>>>(
      xa + 128, k_w + 128, nullptr, nullptr, Kimg + 2097152, 256, 128, 256, 256);
  mgemm_kernel<0, 0, 0><<<dim3(2, 64), 256, 0, stream>>>(
      xa,       v_w,       nullptr, nullptr, Vimg,           256, 128, 256, 256);
  mgemm_kernel<0, 0, 0><<<dim3(2, 64), 256, 0, stream>>>(
      xa + 128, v_w + 128, nullptr, nullptr, Vimg + 2097152, 256, 128, 256, 256);
  // 6. bilinear gather -> kk/vv
  gather_kernel<<<dim3(8, 64, 2), 256, 0, stream>>>(
      (const unsigned short*)Kimg, (const unsigned short*)Vimg,
      rows, cols, k_b, v_b, kkb, vvb);
  // 7. MFMA fused attention
  attn_kernel<<<1024, 256, 0, stream>>>(qb, kkb, vvb, pe, aout);
  // 8. proj + residual(x NCHW) -> x2 NHWC
  mgemm_kernel<0, 1, 0><<<dim3(2, 64), 256, 0, stream>>>(
      aout, pjw, pjb, (const void*)x, x2, 256, 256, 256, 256);
  // 9. LN2 (NHWC)
  ln2_kernel<<<256, 256, 0, stream>>>(x2, ln2g, ln2b, xm);
  // 10. MLP1 + GELU -> hdn NHWC
  mgemm_kernel<0, 0, 1><<<dim3(8, 64), 256, 0, stream>>>(
      xm, w1, b1, nullptr, hdn, 1024, 256, 256, 256);
  // 11. MLP2 + residual(x2 NHWC) -> f32 NCHW d_out
  mgemm_kernel<1, 2, 0><<<dim3(2, 64), 256, 0, stream>>>(
      hdn, w2, b2, (const void*)x2, outp, 256, 1024, 1024, 1024);
}

// Round 6
// 413.581 us; speedup vs baseline: 3.3132x; 1.1341x over previous
//
#include <hip/hip_runtime.h>
#include <hip/hip_bf16.h>
#include <math.h>

// CBiAFormerBlock fused implementation, round 6.
// Change vs r5 (PASS, 469us): gather_kernel ELIMINATED. The kk/vv HBM round
// trip (128MB write + 128MB read, 126us dispatch) is replaced by in-kernel
// gathering inside attn: each (b,head,nw) block bilinear-gathers only its
// head's 32-channel slice of Kimg/Vimg per 64-r chunk (coalesced 16B corner
// loads, weights recomputed inline from rows/cols). Algebraic folds:
//  - k_b dropped: q.(k+kb) adds a per-q constant to all scores -> softmax-inv.
//  - v_b added post-normalization: sum_r P(v+vb)/l = O/l + vb  (sum P/l = 1).
// V-tile transposed via LDS (vtmp->vs). offgrid output re-laid as [bg][nw][r]
// for r-coalesced coord loads. Everything else identical to r5.

typedef __hip_bfloat16 bf16;
typedef __bf16 bf16x8 __attribute__((ext_vector_type(8)));
typedef float f32x4 __attribute__((ext_vector_type(4)));

union U16x8 { uint4 u4; unsigned short us[8]; };

__device__ __forceinline__ float cvt(float x) { return x; }
__device__ __forceinline__ float cvt(bf16 x) { return __bfloat162float(x); }
__device__ __forceinline__ float b2f(unsigned short u) {
  union { float f; unsigned int v; } x; x.v = ((unsigned int)u) << 16; return x.f;
}
__device__ __forceinline__ unsigned short f2b(float f) {
  bf16 h = __float2bfloat16(f);
  return *reinterpret_cast<unsigned short*>(&h);
}
__device__ __forceinline__ float gelu_f(float x) {
  return 0.5f * x * (1.0f + erff(x * 0.7071067811865475f));
}

// ---------------- LN1: NCHW f32 in -> NHWC bf16 out ------------------------
__global__ __launch_bounds__(256) void ln1_kernel(
    const float* __restrict__ x, const float* __restrict__ g,
    const float* __restrict__ bta, bf16* __restrict__ out)
{
  __shared__ float s1[8][32], s2[8][32];
  __shared__ unsigned short tb[32][264];
  int t = threadIdx.x;
  int pos = t & 31, cs = t >> 5;
  int p = blockIdx.x * 32 + pos;
  int bb = p >> 12, hw = p & 4095;
  const float* xp = x + (size_t)bb * 256 * 4096 + hw;
  float vloc[32];
  float sum = 0.f, ss = 0.f;
#pragma unroll
  for (int i = 0; i < 32; ++i) {
    float v = xp[(size_t)(cs * 32 + i) * 4096];
    vloc[i] = v; sum += v; ss += v * v;
  }
  s1[cs][pos] = sum; s2[cs][pos] = ss;
  __syncthreads();
  if (cs == 0) {
    float S = 0.f, Q = 0.f;
#pragma unroll
    for (int i = 0; i < 8; ++i) { S += s1[i][pos]; Q += s2[i][pos]; }
    float mu = S * (1.f / 256.f);
    float var = Q * (1.f / 256.f) - mu * mu;
    s1[0][pos] = mu;
    s2[0][pos] = rsqrtf(var + 1e-5f);
  }
  __syncthreads();
  float mu = s1[0][pos], rs = s2[0][pos];
#pragma unroll
  for (int i = 0; i < 32; ++i) {
    int c = cs * 32 + i;
    tb[pos][c] = f2b((vloc[i] - mu) * rs * g[c] + bta[c]);
  }
  __syncthreads();
  int px = t >> 3, grp = t & 7;
  bf16* op = out + ((size_t)blockIdx.x * 32 + px) * 256 + grp * 32;
#pragma unroll
  for (int q = 0; q < 4; ++q)
    *(uint4*)(op + q * 8) = *(const uint4*)&tb[px][grp * 32 + q * 8];
}

// ---------------- LN2: NHWC bf16 in -> NHWC bf16 out -----------------------
__global__ __launch_bounds__(256) void ln2_kernel(
    const bf16* __restrict__ xin, const float* __restrict__ g,
    const float* __restrict__ bta, bf16* __restrict__ out)
{
  __shared__ float sa[8][32], sb[8][32];
  __shared__ float mu_s[32], rs_s[32];
  int t = threadIdx.x;
  int px = t >> 3, grp = t & 7;
  size_t p = (size_t)blockIdx.x * 32 + px;
  const bf16* xp = xin + p * 256 + grp * 32;
  float v[32]; float sum = 0.f, ss = 0.f;
#pragma unroll
  for (int q = 0; q < 4; ++q) {
    U16x8 u; u.u4 = *(const uint4*)(xp + q * 8);
#pragma unroll
    for (int j = 0; j < 8; ++j) {
      float f = b2f(u.us[j]); v[q * 8 + j] = f; sum += f; ss += f * f;
    }
  }
  sa[grp][px] = sum; sb[grp][px] = ss;
  __syncthreads();
  if (t < 32) {
    float S = 0.f, Q = 0.f;
#pragma unroll
    for (int i = 0; i < 8; ++i) { S += sa[i][t]; Q += sb[i][t]; }
    float mu = S * (1.f / 256.f);
    mu_s[t] = mu;
    rs_s[t] = rsqrtf(Q * (1.f / 256.f) - mu * mu + 1e-5f);
  }
  __syncthreads();
  float mu = mu_s[px], rs = rs_s[px];
  bf16* op = out + p * 256 + grp * 32;
#pragma unroll
  for (int q = 0; q < 4; ++q) {
    U16x8 o;
#pragma unroll
    for (int j = 0; j < 8; ++j) {
      int c = grp * 32 + q * 8 + j;
      o.us[j] = f2b((v[q * 8 + j] - mu) * rs * g[c] + bta[c]);
    }
    *(uint4*)(op + q * 8) = o.u4;
  }
}

// ---------------- MFMA GEMM (NHWC): out[p][o] = sum_c A[p][c] W[o][c] ------
template<int OUTM, int RESM, int ACT>
__global__ __launch_bounds__(256) void mgemm_kernel(
    const bf16* __restrict__ A, const float* __restrict__ Bw,
    const float* __restrict__ bias, const void* __restrict__ res,
    void* __restrict__ out, int N, int K, int lda, int ldb)
{
  constexpr int BK = 64;
  __shared__ unsigned short As[128][BK + 8];
  __shared__ unsigned short Bs[128][BK + 8];
  int t = threadIdx.x;
  int m0 = blockIdx.y * 128, n0 = blockIdx.x * 128;
  int lane = t & 63, w = t >> 6;
  int l15 = lane & 15, quad = lane >> 4;
  int wm = (w >> 1) * 64, wn = (w & 1) * 64;
  f32x4 acc[4][4];
#pragma unroll
  for (int mt = 0; mt < 4; ++mt)
#pragma unroll
    for (int nt = 0; nt < 4; ++nt) acc[mt][nt] = (f32x4){0.f, 0.f, 0.f, 0.f};

  for (int k0 = 0; k0 < K; k0 += BK) {
#pragma unroll
    for (int i = 0; i < 4; ++i) {
      int idx = t + i * 256;
      int m = idx >> 3, oc = (idx & 7) * 8;
      *(uint4*)&As[m][oc] = *(const uint4*)(A + (size_t)(m0 + m) * lda + k0 + oc);
    }
    {
      int n = t >> 1, h = (t & 1) * 32;
      const float* bp = Bw + (size_t)(n0 + n) * ldb + k0 + h;
#pragma unroll
      for (int q = 0; q < 2; ++q) {
        float4 f0 = *(const float4*)(bp + q * 16);
        float4 f1 = *(const float4*)(bp + q * 16 + 4);
        float4 f2 = *(const float4*)(bp + q * 16 + 8);
        float4 f3 = *(const float4*)(bp + q * 16 + 12);
        U16x8 u0, u1;
        u0.us[0] = f2b(f0.x); u0.us[1] = f2b(f0.y); u0.us[2] = f2b(f0.z); u0.us[3] = f2b(f0.w);
        u0.us[4] = f2b(f1.x); u0.us[5] = f2b(f1.y); u0.us[6] = f2b(f1.z); u0.us[7] = f2b(f1.w);
        u1.us[0] = f2b(f2.x); u1.us[1] = f2b(f2.y); u1.us[2] = f2b(f2.z); u1.us[3] = f2b(f2.w);
        u1.us[4] = f2b(f3.x); u1.us[5] = f2b(f3.y); u1.us[6] = f2b(f3.z); u1.us[7] = f2b(f3.w);
        *(uint4*)&Bs[n][h + q * 16] = u0.u4;
        *(uint4*)&Bs[n][h + q * 16 + 8] = u1.u4;
      }
    }
    __syncthreads();
#pragma unroll
    for (int ks = 0; ks < 2; ++ks) {
      bf16x8 af[4], bfr[4];
#pragma unroll
      for (int mt = 0; mt < 4; ++mt)
        af[mt] = __builtin_bit_cast(bf16x8,
            *(const uint4*)&As[wm + mt * 16 + l15][ks * 32 + quad * 8]);
#pragma unroll
      for (int nt = 0; nt < 4; ++nt)
        bfr[nt] = __builtin_bit_cast(bf16x8,
            *(const uint4*)&Bs[wn + nt * 16 + l15][ks * 32 + quad * 8]);
#pragma unroll
      for (int mt = 0; mt < 4; ++mt)
#pragma unroll
        for (int nt = 0; nt < 4; ++nt)
          acc[mt][nt] = __builtin_amdgcn_mfma_f32_16x16x32_bf16(
              af[mt], bfr[nt], acc[mt][nt], 0, 0, 0);
    }
    __syncthreads();
  }
  float bv[4];
#pragma unroll
  for (int nt = 0; nt < 4; ++nt)
    bv[nt] = bias ? bias[n0 + wn + nt * 16 + l15] : 0.f;
#pragma unroll
  for (int mt = 0; mt < 4; ++mt) {
#pragma unroll
    for (int nt = 0; nt < 4; ++nt) {
#pragma unroll
      for (int reg = 0; reg < 4; ++reg) {
        int m = m0 + wm + mt * 16 + quad * 4 + reg;
        int n = n0 + wn + nt * 16 + l15;
        float v = acc[mt][nt][reg] + bv[nt];
        if constexpr (ACT == 1) v = gelu_f(v);
        if constexpr (RESM == 1)
          v += ((const float*)res)[((size_t)(m >> 12) * 256 + n) * 4096 + (m & 4095)];
        if constexpr (RESM == 2)
          v += b2f(((const unsigned short*)res)[(size_t)m * 256 + n]);
        if constexpr (OUTM == 0)
          ((unsigned short*)out)[(size_t)m * N + n] = f2b(v);
        else
          ((float*)out)[((size_t)(m >> 12) * 256 + n) * 4096 + (m & 4095)] = v;
      }
    }
  }
}

// ---------------- depthwise 3x3 stride-2 pad-1 conv, NHWC-128 --------------
template<typename T, int IC>
__global__ __launch_bounds__(256) void dwconv_kernel(
    const T* __restrict__ in, const float* __restrict__ wgt,
    float* __restrict__ out, int Hi, int Wi, int Ho, int Wo, int fuse,
    const float* __restrict__ bg_, const float* __restrict__ bb_,
    const float* __restrict__ bm_, const float* __restrict__ bv_)
{
  int idx = blockIdx.x * 256 + threadIdx.x;
  int c = idx & 127;
  int pp = idx >> 7;
  int ow = pp % Wo, oh = (pp / Wo) % Ho, bgi = pp / (Wo * Ho);
  const T* ip;
  if constexpr (IC == 256)
    ip = in + ((size_t)(bgi >> 1) * 4096) * 256 + (bgi & 1) * 128 + c;
  else
    ip = in + ((size_t)bgi * Hi * Wi) * 128 + c;
  float acc = 0.f;
#pragma unroll
  for (int ky = 0; ky < 3; ++ky) {
    int ih = oh * 2 - 1 + ky;
    if ((unsigned)ih >= (unsigned)Hi) continue;
#pragma unroll
    for (int kx = 0; kx < 3; ++kx) {
      int iw = ow * 2 - 1 + kx;
      if ((unsigned)iw >= (unsigned)Wi) continue;
      acc += wgt[c * 9 + ky * 3 + kx] * cvt(ip[(size_t)(ih * Wi + iw) * IC]);
    }
  }
  if (fuse) {
    acc = (acc - bm_[c]) * rsqrtf(bv_[c] + 1e-5f) * bg_[c] + bb_[c];
    acc = gelu_f(acc);
  }
  out[idx] = acc;
}

// ---------------- offset head: off4_w @ o -> tanh -> grid (pixel coords) ----
// Output layout [bg][nw][r] so attn coord loads are r-coalesced.
__global__ __launch_bounds__(256) void offgrid_kernel(
    const float* __restrict__ o, const float* __restrict__ w4,
    float* __restrict__ rows, float* __restrict__ cols)
{
  int idx = blockIdx.x * 256 + threadIdx.x;
  int nw = idx & 63;
  int r = (idx >> 6) & 1023;
  int coord = (idx >> 16) & 1;
  int bg = idx >> 17;
  const float* op = o + ((size_t)bg * 64 + nw) * 128;
  const float* wp = w4 + ((size_t)coord * 1024 + r) * 128;
  float acc = 0.f;
  for (int c = 0; c < 128; ++c) acc += wp[c] * op[c];
  float val = tanhf(acc) * (2.0f / 64.0f);
  int rc = coord ? (r & 31) : (r >> 5);
  float ref = rc * (4.0f / 63.0f) - 1.0f;
  float pix = (val + ref + 1.0f) * 31.5f;
  (coord ? cols : rows)[(size_t)bg * 65536 + nw * 1024 + r] = pix;
}

// ---------------- MFMA fused deformable window attention -------------------
// One block per (b, head, nw). Gathers its head's 32-ch K/V slice per chunk
// directly from Kimg/Vimg (no kk/vv round trip). k_b dropped (softmax-inv),
// v_b added post-normalization.
__global__ __launch_bounds__(256) void attn_kernel(
    const bf16* __restrict__ qbuf, const unsigned short* __restrict__ Kimg,
    const unsigned short* __restrict__ Vimg, const float* __restrict__ rows_,
    const float* __restrict__ cols_, const float* __restrict__ vbv,
    const float* __restrict__ pe, bf16* __restrict__ aout)
{
  __shared__ unsigned short qs[64][40];     // 5120 B
  __shared__ unsigned short ks[64][40];     // 5120 B
  __shared__ unsigned short vtmp[64][40];   // 5120 B
  __shared__ unsigned short vs[32][72];     // 4608 B
  __shared__ unsigned short Ps[64][72];     // 9216 B
  __shared__ float pes[70][72];             // 20160 B  (total 49,344 B)

  int blk = blockIdx.x;
  int nw = blk & 63, head = (blk >> 6) & 7, b = blk >> 9;
  int wh = nw >> 3, ww = nw & 7;
  int t = threadIdx.x;
  int lane = t & 63, w = t >> 6;
  int l15 = lane & 15, quad = lane >> 4;
  int qc0 = head * 32;

  // stage Q from NHWC, scaled by C^-0.5 = 1/16
  {
    int qt = t >> 2, oct = t & 3;
    int h = wh * 8 + (qt >> 3), wcol = ww * 8 + (qt & 7);
    const bf16* src = qbuf + ((size_t)b * 4096 + h * 64 + wcol) * 256 + qc0 + oct * 8;
    U16x8 u; u.u4 = *(const uint4*)src;
    U16x8 o;
#pragma unroll
    for (int j = 0; j < 8; ++j) o.us[j] = f2b(b2f(u.us[j]) * 0.0625f);
    *(uint4*)&qs[qt][oct * 8] = o.u4;
  }
  int ry0 = 56 - wh * 8, rx0 = 56 - ww * 8;
  for (int i = t; i < 70 * 70; i += 256) {
    int yy = i / 70, xx = i % 70;
    pes[yy][xx] = pe[(size_t)head * 16129 + (ry0 + yy) * 127 + rx0 + xx];
  }
  __syncthreads();

  bf16x8 aQ;
  {
    uint4 u = *(const uint4*)&qs[w * 16 + l15][quad * 8];
    aQ = __builtin_bit_cast(bf16x8, u);
  }
  float m[4] = {-1e30f, -1e30f, -1e30f, -1e30f};
  float l[4] = {0.f, 0.f, 0.f, 0.f};
  f32x4 oacc[2];
  oacc[0] = (f32x4){0.f, 0.f, 0.f, 0.f};
  oacc[1] = (f32x4){0.f, 0.f, 0.f, 0.f};
  int qh[4], qw_[4];
#pragma unroll
  for (int reg = 0; reg < 4; ++reg) {
    int q = w * 16 + quad * 4 + reg;
    qh[reg] = q >> 3; qw_[reg] = q & 7;
  }

  int gr_r = t >> 2, gr_seg = t & 3;   // gather mapping: one (r, 8ch-seg)/thread
  for (int rc0 = 0; rc0 < 1024; rc0 += 64) {
    // ---- in-kernel bilinear gather of this head's 32-ch slice ----
    {
      float aK[8], aV[8];
#pragma unroll
      for (int j = 0; j < 8; ++j) { aK[j] = 0.f; aV[j] = 0.f; }
#pragma unroll
      for (int g = 0; g < 2; ++g) {
        size_t cbase = ((size_t)(b * 2 + g) * 64 + nw) * 1024 + rc0 + gr_r;
        float rowf = rows_[cbase];
        float colf = cols_[cbase];
        float r0f = floorf(rowf), c0f = floorf(colf);
        float wr = rowf - r0f, wc = colf - c0f;
        int r0 = (int)r0f, c0 = (int)c0f;
        bool rv0 = ((unsigned)r0 < 64u), rv1 = ((unsigned)(r0 + 1) < 64u);
        bool cv0 = ((unsigned)c0 < 64u), cv1 = ((unsigned)(c0 + 1) < 64u);
        float w00 = (rv0 && cv0) ? (1.f - wr) * (1.f - wc) : 0.f;
        float w01 = (rv0 && cv1) ? (1.f - wr) * wc : 0.f;
        float w10 = (rv1 && cv0) ? wr * (1.f - wc) : 0.f;
        float w11 = (rv1 && cv1) ? wr * wc : 0.f;
        int ra = min(max(r0, 0), 63), rb2 = min(max(r0 + 1, 0), 63);
        int ca = min(max(c0, 0), 63), cb2 = min(max(c0 + 1, 0), 63);
        size_t pb = ((size_t)g * 8192 + (size_t)b * 4096) * 256 + qc0 + gr_seg * 8;
        size_t o00 = pb + (size_t)(ra * 64 + ca) * 256;
        size_t o01 = pb + (size_t)(ra * 64 + cb2) * 256;
        size_t o10 = pb + (size_t)(rb2 * 64 + ca) * 256;
        size_t o11 = pb + (size_t)(rb2 * 64 + cb2) * 256;
        U16x8 k00, k01, k10, k11, v00, v01, v10, v11;
        k00.u4 = *(const uint4*)(Kimg + o00); v00.u4 = *(const uint4*)(Vimg + o00);
        k01.u4 = *(const uint4*)(Kimg + o01); v01.u4 = *(const uint4*)(Vimg + o01);
        k10.u4 = *(const uint4*)(Kimg + o10); v10.u4 = *(const uint4*)(Vimg + o10);
        k11.u4 = *(const uint4*)(Kimg + o11); v11.u4 = *(const uint4*)(Vimg + o11);
#pragma unroll
        for (int j = 0; j < 8; ++j) {
          aK[j] += w00 * b2f(k00.us[j]) + w01 * b2f(k01.us[j])
                 + w10 * b2f(k10.us[j]) + w11 * b2f(k11.us[j]);
          aV[j] += w00 * b2f(v00.us[j]) + w01 * b2f(v01.us[j])
                 + w10 * b2f(v10.us[j]) + w11 * b2f(v11.us[j]);
        }
      }
      U16x8 ok, ov;
#pragma unroll
      for (int j = 0; j < 8; ++j) { ok.us[j] = f2b(aK[j]); ov.us[j] = f2b(aV[j]); }
      *(uint4*)&ks[gr_r][gr_seg * 8] = ok.u4;
      *(uint4*)&vtmp[gr_r][gr_seg * 8] = ov.u4;
    }
    __syncthreads();
    // ---- transpose V tile: vs[hc][r] ----
    {
      int hc = t & 31, rg = t >> 5;
      U16x8 u;
#pragma unroll
      for (int i2 = 0; i2 < 8; ++i2) u.us[i2] = vtmp[rg * 8 + i2][hc];
      *(uint4*)&vs[hc][rg * 8] = u.u4;
    }
    __syncthreads();

    // ---- S = Q.K^T via 4 MFMAs ----
    f32x4 s[4];
#pragma unroll
    for (int nt = 0; nt < 4; ++nt) {
      uint4 u = *(const uint4*)&ks[nt * 16 + l15][quad * 8];
      bf16x8 bK = __builtin_bit_cast(bf16x8, u);
      f32x4 z = (f32x4){0.f, 0.f, 0.f, 0.f};
      s[nt] = __builtin_amdgcn_mfma_f32_16x16x32_bf16(aQ, bK, z, 0, 0, 0);
    }
#pragma unroll
    for (int nt = 0; nt < 4; ++nt) {
      int rg_ = nt * 16 + l15;
      int rrow = (rc0 + rg_) >> 5, rcol = rg_ & 31;
#pragma unroll
      for (int reg = 0; reg < 4; ++reg)
        s[nt][reg] += pes[2 * rrow + 7 - qh[reg]][2 * rcol + 7 - qw_[reg]];
    }
    // ---- online softmax (quad-local state) ----
    float alpha[4];
#pragma unroll
    for (int reg = 0; reg < 4; ++reg) {
      float mx = fmaxf(fmaxf(s[0][reg], s[1][reg]), fmaxf(s[2][reg], s[3][reg]));
      mx = fmaxf(mx, __shfl_xor(mx, 1, 64));
      mx = fmaxf(mx, __shfl_xor(mx, 2, 64));
      mx = fmaxf(mx, __shfl_xor(mx, 4, 64));
      mx = fmaxf(mx, __shfl_xor(mx, 8, 64));
      float mn = fmaxf(m[reg], mx);
      alpha[reg] = __expf(m[reg] - mn);
      m[reg] = mn;
      float ps = 0.f;
#pragma unroll
      for (int nt = 0; nt < 4; ++nt) {
        float p = __expf(s[nt][reg] - mn);
        Ps[w * 16 + quad * 4 + reg][nt * 16 + l15] = f2b(p);
        ps += p;
      }
      ps += __shfl_xor(ps, 1, 64);
      ps += __shfl_xor(ps, 2, 64);
      ps += __shfl_xor(ps, 4, 64);
      ps += __shfl_xor(ps, 8, 64);
      l[reg] = l[reg] * alpha[reg] + ps;
      oacc[0][reg] *= alpha[reg];
      oacc[1][reg] *= alpha[reg];
    }
    // ---- O += P.V ----
#pragma unroll
    for (int kst = 0; kst < 2; ++kst) {
      uint4 up = *(const uint4*)&Ps[w * 16 + l15][kst * 32 + quad * 8];
      bf16x8 pA = __builtin_bit_cast(bf16x8, up);
#pragma unroll
      for (int nt2 = 0; nt2 < 2; ++nt2) {
        uint4 uv = *(const uint4*)&vs[nt2 * 16 + l15][kst * 32 + quad * 8];
        bf16x8 vB = __builtin_bit_cast(bf16x8, uv);
        oacc[nt2] = __builtin_amdgcn_mfma_f32_16x16x32_bf16(pA, vB, oacc[nt2], 0, 0, 0);
      }
    }
    __syncthreads();
  }
  // epilogue: O/l + v_b, NHWC writes
#pragma unroll
  for (int nt2 = 0; nt2 < 2; ++nt2) {
    float vbias = vbv[qc0 + nt2 * 16 + l15];
#pragma unroll
    for (int reg = 0; reg < 4; ++reg) {
      size_t p = (size_t)b * 4096 + (wh * 8 + qh[reg]) * 64 + ww * 8 + qw_[reg];
      aout[p * 256 + qc0 + nt2 * 16 + l15] =
          __float2bfloat16(oacc[nt2][reg] / l[reg] + vbias);
    }
  }
}

// ---------------------------------------------------------------------------
extern "C" void kernel_launch(void* const* d_in, const int* in_sizes, int n_in,
                              void* d_out, int out_size, void* d_ws, size_t ws_size,
                              hipStream_t stream) {
  (void)in_sizes; (void)n_in; (void)out_size; (void)ws_size;
  const float* x     = (const float*)d_in[0];
  const float* ln1g  = (const float*)d_in[1];
  const float* ln1b  = (const float*)d_in[2];
  const float* q_w   = (const float*)d_in[3];
  const float* q_b   = (const float*)d_in[4];
  const float* k_w   = (const float*)d_in[5];
  const float* k_b   = (const float*)d_in[6];
  const float* v_w   = (const float*)d_in[7];
  const float* v_b   = (const float*)d_in[8];
  const float* off1w = (const float*)d_in[9];
  const float* off2w = (const float*)d_in[10];
  const float* off3w = (const float*)d_in[11];
  const float* bng   = (const float*)d_in[12];
  const float* bnb   = (const float*)d_in[13];
  const float* bnm   = (const float*)d_in[14];
  const float* bnv   = (const float*)d_in[15];
  const float* off4w = (const float*)d_in[16];
  const float* pe    = (const float*)d_in[17];
  const float* pjw   = (const float*)d_in[18];
  const float* pjb   = (const float*)d_in[19];
  const float* ln2g  = (const float*)d_in[20];
  const float* ln2b  = (const float*)d_in[21];
  const float* w1    = (const float*)d_in[22];
  const float* b1    = (const float*)d_in[23];
  const float* w2    = (const float*)d_in[24];
  const float* b2    = (const float*)d_in[25];
  (void)k_b;
  float* outp = (float*)d_out;

  // workspace arena (~34 MB), all offsets 16B-aligned; act buffers NHWC
  char* W = (char*)d_ws;
  bf16*  xa   = (bf16*) (W + 0);          // [8192][256] bf16; reused as aout
  bf16*  qb   = (bf16*) (W + 4194304);    // [8192][256]; reused as xm
  float* dw1  = (float*)(W + 8388608);    // [4][1024][128] f32
  float* dw2  = (float*)(W + 10485760);   // [4][256][128]
  float* dw3  = (float*)(W + 11010048);   // [4][64][128]
  float* rows = (float*)(W + 11141120);   // [4][64][1024] f32
  float* cols = (float*)(W + 12189696);   // [4][64][1024]
  bf16*  Kimg = (bf16*) (W + 13238272);   // [2g][8192][256] bf16
  bf16*  Vimg = (bf16*) (W + 21626880);   // [2g][8192][256]
  bf16*  x2   = (bf16*) (W + 30015488);   // [8192][256]
  bf16*  aout = xa;
  bf16*  xm   = qb;
  bf16*  hdn  = Kimg;                     // [8192][1024] over Kimg+Vimg (dead)

  // 1. LN1 (NCHW f32 -> NHWC bf16)
  ln1_kernel<<<256, 256, 0, stream>>>(x, ln1g, ln1b, xa);
  // 2. q = xa @ q_w^T + q_b
  mgemm_kernel<0, 0, 0><<<dim3(2, 64), 256, 0, stream>>>(
      xa, q_w, q_b, nullptr, qb, 256, 256, 256, 256);
  // 3. offset branch (NHWC-128)
  dwconv_kernel<bf16, 256><<<2048, 256, 0, stream>>>(qb, off1w, dw1, 64, 64, 32, 32, 0,
                                                     nullptr, nullptr, nullptr, nullptr);
  dwconv_kernel<float, 128><<<512, 256, 0, stream>>>(dw1, off2w, dw2, 32, 32, 16, 16, 0,
                                                     nullptr, nullptr, nullptr, nullptr);
  dwconv_kernel<float, 128><<<128, 256, 0, stream>>>(dw2, off3w, dw3, 16, 16, 8, 8, 1,
                                                     bng, bnb, bnm, bnv);
  // 4. sampling grid ([bg][nw][r] layout)
  offgrid_kernel<<<2048, 256, 0, stream>>>(dw3, off4w, rows, cols);
  // 5. Kimg/Vimg per group
  mgemm_kernel<0, 0, 0><<<dim3(2, 64), 256, 0, stream>>>(
      xa,       k_w,       nullptr, nullptr, Kimg,           256, 128, 256, 256);
  mgemm_kernel<0, 0, 0><<<dim3(2, 64), 256, 0, stream>>>(
      xa + 128, k_w + 128, nullptr, nullptr, Kimg + 2097152, 256, 128, 256, 256);
  mgemm_kernel<0, 0, 0><<<dim3(2, 64), 256, 0, stream>>>(
      xa,       v_w,       nullptr, nullptr, Vimg,           256, 128, 256, 256);
  mgemm_kernel<0, 0, 0><<<dim3(2, 64), 256, 0, stream>>>(
      xa + 128, v_w + 128, nullptr, nullptr, Vimg + 2097152, 256, 128, 256, 256);
  // 6. fused attention (in-kernel gather; no kk/vv round trip)
  attn_kernel<<<1024, 256, 0, stream>>>(
      qb, (const unsigned short*)Kimg, (const unsigned short*)Vimg,
      rows, cols, v_b, pe, aout);
  // 7. proj + residual(x NCHW) -> x2 NHWC
  mgemm_kernel<0, 1, 0><<<dim3(2, 64), 256, 0, stream>>>(
      aout, pjw, pjb, (const void*)x, x2, 256, 256, 256, 256);
  // 8. LN2
  ln2_kernel<<<256, 256, 0, stream>>>(x2, ln2g, ln2b, xm);
  // 9. MLP1 + GELU
  mgemm_kernel<0, 0, 1><<<dim3(8, 64), 256, 0, stream>>>(
      xm, w1, b1, nullptr, hdn, 1024, 256, 256, 256);
  // 10. MLP2 + residual(x2) -> f32 NCHW d_out
  mgemm_kernel<1, 2, 0><<<dim3(2, 64), 256, 0, stream>>>(
      hdn, w2, b2, (const void*)x2, outp, 256, 1024, 1024, 1024);
}

// Round 7
// 406.106 us; speedup vs baseline: 3.3742x; 1.0184x over previous
//
#include <hip/hip_runtime.h>
#include <hip/hip_bf16.h>
#include <math.h>

// CBiAFormerBlock fused implementation, round 7.
// Changes vs r6 (PASS, 413us):
//  - attn: LDS 49.6->29.5KB (pes bf16, Ps/Q union, vtmp dropped via direct
//    transposed V writes), gather remapped lane=r (coalesced coords), one
//    fewer barrier per chunk. Occupancy 3->4+ blocks/CU.
//  - mgemm: BN 128->64 (grid.x=N/64 -> 256+ blocks, full GPU). New epilogues:
//    OUTM=1 writes NCHW f32 via LDS transpose (coalesced 512B rows);
//    RESM=1 reads f32 NHWC residual (x_nhwc, coalesced); OUTM=3 fuses the
//    offset-grid head (tanh+ref+pixel-coords) -> offgrid_kernel deleted.
//  - ln1 additionally emits x_nhwc f32 (for proj residual).
//  - dw3 output bf16 (feeds offgrid-mgemm as A operand).

typedef __hip_bfloat16 bf16;
typedef __bf16 bf16x8 __attribute__((ext_vector_type(8)));
typedef float f32x4 __attribute__((ext_vector_type(4)));

union U16x8 { uint4 u4; unsigned short us[8]; };

__device__ __forceinline__ float cvt(float x) { return x; }
__device__ __forceinline__ float cvt(bf16 x) { return __bfloat162float(x); }
__device__ __forceinline__ float b2f(unsigned short u) {
  union { float f; unsigned int v; } x; x.v = ((unsigned int)u) << 16; return x.f;
}
__device__ __forceinline__ unsigned short f2b(float f) {
  bf16 h = __float2bfloat16(f);
  return *reinterpret_cast<unsigned short*>(&h);
}
__device__ __forceinline__ float gelu_f(float x) {
  return 0.5f * x * (1.0f + erff(x * 0.7071067811865475f));
}
__device__ __forceinline__ void stout(float* p, float v) { *p = v; }
__device__ __forceinline__ void stout(bf16* p, float v) { *p = __float2bfloat16(v); }

// ---------------- LN1: NCHW f32 in -> NHWC bf16 out + raw x NHWC f32 -------
__global__ __launch_bounds__(256) void ln1_kernel(
    const float* __restrict__ x, const float* __restrict__ g,
    const float* __restrict__ bta, bf16* __restrict__ out,
    float* __restrict__ xnhwc)
{
  __shared__ float s1[8][32], s2[8][32];
  __shared__ unsigned short tb[32][264];
  int t = threadIdx.x;
  int pos = t & 31, cs = t >> 5;
  int p = blockIdx.x * 32 + pos;
  int bb = p >> 12, hw = p & 4095;
  const float* xp = x + (size_t)bb * 256 * 4096 + hw;
  float vloc[32];
  float sum = 0.f, ss = 0.f;
#pragma unroll
  for (int i = 0; i < 32; ++i) {
    float v = xp[(size_t)(cs * 32 + i) * 4096];
    vloc[i] = v; sum += v; ss += v * v;
  }
  s1[cs][pos] = sum; s2[cs][pos] = ss;
  // raw x transpose write (for proj residual), float4 coalesced per thread
  {
    float* xo = xnhwc + (size_t)p * 256 + cs * 32;
#pragma unroll
    for (int qd = 0; qd < 8; ++qd)
      *(float4*)(xo + qd * 4) = make_float4(vloc[qd*4], vloc[qd*4+1],
                                            vloc[qd*4+2], vloc[qd*4+3]);
  }
  __syncthreads();
  if (cs == 0) {
    float S = 0.f, Q = 0.f;
#pragma unroll
    for (int i = 0; i < 8; ++i) { S += s1[i][pos]; Q += s2[i][pos]; }
    float mu = S * (1.f / 256.f);
    float var = Q * (1.f / 256.f) - mu * mu;
    s1[0][pos] = mu;
    s2[0][pos] = rsqrtf(var + 1e-5f);
  }
  __syncthreads();
  float mu = s1[0][pos], rs = s2[0][pos];
#pragma unroll
  for (int i = 0; i < 32; ++i) {
    int c = cs * 32 + i;
    tb[pos][c] = f2b((vloc[i] - mu) * rs * g[c] + bta[c]);
  }
  __syncthreads();
  int px = t >> 3, grp = t & 7;
  bf16* op = out + ((size_t)blockIdx.x * 32 + px) * 256 + grp * 32;
#pragma unroll
  for (int q = 0; q < 4; ++q)
    *(uint4*)(op + q * 8) = *(const uint4*)&tb[px][grp * 32 + q * 8];
}

// ---------------- LN2: NHWC bf16 in -> NHWC bf16 out -----------------------
__global__ __launch_bounds__(256) void ln2_kernel(
    const bf16* __restrict__ xin, const float* __restrict__ g,
    const float* __restrict__ bta, bf16* __restrict__ out)
{
  __shared__ float sa[8][32], sb[8][32];
  __shared__ float mu_s[32], rs_s[32];
  int t = threadIdx.x;
  int px = t >> 3, grp = t & 7;
  size_t p = (size_t)blockIdx.x * 32 + px;
  const bf16* xp = xin + p * 256 + grp * 32;
  float v[32]; float sum = 0.f, ss = 0.f;
#pragma unroll
  for (int q = 0; q < 4; ++q) {
    U16x8 u; u.u4 = *(const uint4*)(xp + q * 8);
#pragma unroll
    for (int j = 0; j < 8; ++j) {
      float f = b2f(u.us[j]); v[q * 8 + j] = f; sum += f; ss += f * f;
    }
  }
  sa[grp][px] = sum; sb[grp][px] = ss;
  __syncthreads();
  if (t < 32) {
    float S = 0.f, Q = 0.f;
#pragma unroll
    for (int i = 0; i < 8; ++i) { S += sa[i][t]; Q += sb[i][t]; }
    float mu = S * (1.f / 256.f);
    mu_s[t] = mu;
    rs_s[t] = rsqrtf(Q * (1.f / 256.f) - mu * mu + 1e-5f);
  }
  __syncthreads();
  float mu = mu_s[px], rs = rs_s[px];
  bf16* op = out + p * 256 + grp * 32;
#pragma unroll
  for (int q = 0; q < 4; ++q) {
    U16x8 o;
#pragma unroll
    for (int j = 0; j < 8; ++j) {
      int c = grp * 32 + q * 8 + j;
      o.us[j] = f2b((v[q * 8 + j] - mu) * rs * g[c] + bta[c]);
    }
    *(uint4*)(op + q * 8) = o.u4;
  }
}

// ---------------- MFMA GEMM (NHWC): out[p][o] = sum_c A[p][c] W[o][c] ------
// BM=128, BN=64, BK=64; grid (N/64, M/128); 4 waves as 2x2 (64m x 32n each).
// OUTM: 0 = bf16 NHWC [m*N+n]; 1 = f32 NCHW via LDS transpose (coalesced);
//       3 = offset-grid head: tanh -> pixel coords into rows(out)/cols(res).
// RESM: 0 none; 1 f32 NHWC (stride N); 2 bf16 NHWC (stride N). ACT: 1 GELU.
template<int OUTM, int RESM, int ACT>
__global__ __launch_bounds__(256) void mgemm_kernel(
    const bf16* __restrict__ A, const float* __restrict__ Bw,
    const float* __restrict__ bias, const void* __restrict__ res,
    void* __restrict__ out, int N, int K, int lda, int ldb)
{
  constexpr int AB_BYTES = (128 * 72 + 64 * 72) * 2;   // 27648
  constexpr int T_BYTES  = 64 * 133 * 4;               // 34048
  constexpr int SH_BYTES = (OUTM == 1 && T_BYTES > AB_BYTES) ? T_BYTES : AB_BYTES;
  __shared__ __attribute__((aligned(16))) char shraw[SH_BYTES];
  auto As = reinterpret_cast<unsigned short(*)[72]>(shraw);              // [128][72]
  auto Bs = reinterpret_cast<unsigned short(*)[72]>(shraw + 128 * 72 * 2); // [64][72]
  float (*T)[133] = reinterpret_cast<float(*)[133]>(shraw);

  int t = threadIdx.x;
  int m0 = blockIdx.y * 128, n0 = blockIdx.x * 64;
  int lane = t & 63, w = t >> 6;
  int l15 = lane & 15, quad = lane >> 4;
  int wm = (w >> 1) * 64, wn = (w & 1) * 32;
  f32x4 acc[4][2];
#pragma unroll
  for (int mt = 0; mt < 4; ++mt)
#pragma unroll
    for (int nt = 0; nt < 2; ++nt) acc[mt][nt] = (f32x4){0.f, 0.f, 0.f, 0.f};

  for (int k0 = 0; k0 < K; k0 += 64) {
#pragma unroll
    for (int i = 0; i < 4; ++i) {
      int idx = t + i * 256;
      int m = idx >> 3, oc = (idx & 7) * 8;
      *(uint4*)&As[m][oc] = *(const uint4*)(A + (size_t)(m0 + m) * lda + k0 + oc);
    }
    {
      int n = t >> 2, h = (t & 3) * 16;
      const float* bp = Bw + (size_t)(n0 + n) * ldb + k0 + h;
      float4 f0 = *(const float4*)(bp);
      float4 f1 = *(const float4*)(bp + 4);
      float4 f2 = *(const float4*)(bp + 8);
      float4 f3 = *(const float4*)(bp + 12);
      U16x8 u0, u1;
      u0.us[0] = f2b(f0.x); u0.us[1] = f2b(f0.y); u0.us[2] = f2b(f0.z); u0.us[3] = f2b(f0.w);
      u0.us[4] = f2b(f1.x); u0.us[5] = f2b(f1.y); u0.us[6] = f2b(f1.z); u0.us[7] = f2b(f1.w);
      u1.us[0] = f2b(f2.x); u1.us[1] = f2b(f2.y); u1.us[2] = f2b(f2.z); u1.us[3] = f2b(f2.w);
      u1.us[4] = f2b(f3.x); u1.us[5] = f2b(f3.y); u1.us[6] = f2b(f3.z); u1.us[7] = f2b(f3.w);
      *(uint4*)&Bs[n][h] = u0.u4;
      *(uint4*)&Bs[n][h + 8] = u1.u4;
    }
    __syncthreads();
#pragma unroll
    for (int ks = 0; ks < 2; ++ks) {
      bf16x8 af[4], bfr[2];
#pragma unroll
      for (int mt = 0; mt < 4; ++mt)
        af[mt] = __builtin_bit_cast(bf16x8,
            *(const uint4*)&As[wm + mt * 16 + l15][ks * 32 + quad * 8]);
#pragma unroll
      for (int nt = 0; nt < 2; ++nt)
        bfr[nt] = __builtin_bit_cast(bf16x8,
            *(const uint4*)&Bs[wn + nt * 16 + l15][ks * 32 + quad * 8]);
#pragma unroll
      for (int mt = 0; mt < 4; ++mt)
#pragma unroll
        for (int nt = 0; nt < 2; ++nt)
          acc[mt][nt] = __builtin_amdgcn_mfma_f32_16x16x32_bf16(
              af[mt], bfr[nt], acc[mt][nt], 0, 0, 0);
    }
    __syncthreads();
  }
  float bv[2];
#pragma unroll
  for (int nt = 0; nt < 2; ++nt)
    bv[nt] = bias ? bias[n0 + wn + nt * 16 + l15] : 0.f;
#pragma unroll
  for (int mt = 0; mt < 4; ++mt) {
#pragma unroll
    for (int nt = 0; nt < 2; ++nt) {
#pragma unroll
      for (int reg = 0; reg < 4; ++reg) {
        int m = m0 + wm + mt * 16 + quad * 4 + reg;
        int n = n0 + wn + nt * 16 + l15;
        float v = acc[mt][nt][reg] + bv[nt];
        if constexpr (ACT == 1) v = gelu_f(v);
        if constexpr (RESM == 1)
          v += ((const float*)res)[(size_t)m * N + n];
        if constexpr (RESM == 2)
          v += b2f(((const unsigned short*)res)[(size_t)m * N + n]);
        if constexpr (OUTM == 0)
          ((unsigned short*)out)[(size_t)m * N + n] = f2b(v);
        if constexpr (OUTM == 1)
          T[(n - n0)][(m - m0)] = v;
        if constexpr (OUTM == 3) {
          float val = tanhf(v) * (2.0f / 64.0f);
          int coord = n >> 10, r = n & 1023;
          int rc = coord ? (r & 31) : (r >> 5);
          float ref = rc * (4.0f / 63.0f) - 1.0f;
          float pix = (val + ref + 1.0f) * 31.5f;
          float* dst = coord ? (float*)res : (float*)out;
          dst[(size_t)m * 1024 + r] = pix;   // m = bg*64+nw
        }
      }
    }
  }
  if constexpr (OUTM == 1) {
    __syncthreads();
    int nl = t >> 2, seg = t & 3;
    int bI = m0 >> 12, hw0 = m0 & 4095;
    float* op = (float*)out + ((size_t)bI * 256 + n0 + nl) * 4096 + hw0 + seg * 32;
#pragma unroll
    for (int k = 0; k < 32; ++k) op[k] = T[nl][seg * 32 + k];
  }
}

// ---------------- depthwise 3x3 stride-2 pad-1 conv, NHWC-128 --------------
template<typename TI, typename TO, int IC>
__global__ __launch_bounds__(256) void dwconv_kernel(
    const TI* __restrict__ in, const float* __restrict__ wgt,
    TO* __restrict__ out, int Hi, int Wi, int Ho, int Wo, int fuse,
    const float* __restrict__ bg_, const float* __restrict__ bb_,
    const float* __restrict__ bm_, const float* __restrict__ bv_)
{
  int idx = blockIdx.x * 256 + threadIdx.x;
  int c = idx & 127;
  int pp = idx >> 7;
  int ow = pp % Wo, oh = (pp / Wo) % Ho, bgi = pp / (Wo * Ho);
  const TI* ip;
  if constexpr (IC == 256)
    ip = in + ((size_t)(bgi >> 1) * 4096) * 256 + (bgi & 1) * 128 + c;
  else
    ip = in + ((size_t)bgi * Hi * Wi) * 128 + c;
  float acc = 0.f;
#pragma unroll
  for (int ky = 0; ky < 3; ++ky) {
    int ih = oh * 2 - 1 + ky;
    if ((unsigned)ih >= (unsigned)Hi) continue;
#pragma unroll
    for (int kx = 0; kx < 3; ++kx) {
      int iw = ow * 2 - 1 + kx;
      if ((unsigned)iw >= (unsigned)Wi) continue;
      acc += wgt[c * 9 + ky * 3 + kx] * cvt(ip[(size_t)(ih * Wi + iw) * IC]);
    }
  }
  if (fuse) {
    acc = (acc - bm_[c]) * rsqrtf(bv_[c] + 1e-5f) * bg_[c] + bb_[c];
    acc = gelu_f(acc);
  }
  stout(out + idx, acc);
}

// ---------------- MFMA fused deformable window attention -------------------
// One block per (b, head, nw); LDS 29.5KB. Gather mapping: lane=r, wave=seg.
__global__ __launch_bounds__(256) void attn_kernel(
    const bf16* __restrict__ qbuf, const unsigned short* __restrict__ Kimg,
    const unsigned short* __restrict__ Vimg, const float* __restrict__ rows_,
    const float* __restrict__ cols_, const float* __restrict__ vbv,
    const float* __restrict__ pe, bf16* __restrict__ aout)
{
  __shared__ unsigned short ks[64][40];       // 5120 B
  __shared__ unsigned short vs[32][80];       // 5120 B (transposed V)
  __shared__ unsigned short PsQs[64][72];     // 9216 B (Q staged here pre-loop)
  __shared__ unsigned short pesb[70][72];     // 10080 B bf16 posembed
  // total 29,536 B -> 4-5 blocks/CU

  int blk = blockIdx.x;
  int nw = blk & 63, head = (blk >> 6) & 7, b = blk >> 9;
  int wh = nw >> 3, ww = nw & 7;
  int t = threadIdx.x;
  int lane = t & 63, w = t >> 6;
  int l15 = lane & 15, quad = lane >> 4;
  int qc0 = head * 32;

  // stage Q (scaled 1/16) into PsQs
  {
    int qt = t >> 2, oct = t & 3;
    int h = wh * 8 + (qt >> 3), wcol = ww * 8 + (qt & 7);
    const bf16* src = qbuf + ((size_t)b * 4096 + h * 64 + wcol) * 256 + qc0 + oct * 8;
    U16x8 u; u.u4 = *(const uint4*)src;
    U16x8 o;
#pragma unroll
    for (int j = 0; j < 8; ++j) o.us[j] = f2b(b2f(u.us[j]) * 0.0625f);
    *(uint4*)&PsQs[qt][oct * 8] = o.u4;
  }
  int ry0 = 56 - wh * 8, rx0 = 56 - ww * 8;
  for (int i = t; i < 70 * 70; i += 256) {
    int yy = i / 70, xx = i % 70;
    pesb[yy][xx] = f2b(pe[(size_t)head * 16129 + (ry0 + yy) * 127 + rx0 + xx]);
  }
  __syncthreads();

  bf16x8 aQ;
  {
    uint4 u = *(const uint4*)&PsQs[w * 16 + l15][quad * 8];
    aQ = __builtin_bit_cast(bf16x8, u);
  }
  float m[4] = {-1e30f, -1e30f, -1e30f, -1e30f};
  float l[4] = {0.f, 0.f, 0.f, 0.f};
  f32x4 oacc[2];
  oacc[0] = (f32x4){0.f, 0.f, 0.f, 0.f};
  oacc[1] = (f32x4){0.f, 0.f, 0.f, 0.f};

  for (int rc0 = 0; rc0 < 1024; rc0 += 64) {
    // ---- gather: lane = r (coalesced coords), wave = 8-ch segment ----
    {
      float aK[8], aV[8];
#pragma unroll
      for (int j = 0; j < 8; ++j) { aK[j] = 0.f; aV[j] = 0.f; }
#pragma unroll
      for (int g = 0; g < 2; ++g) {
        size_t cbase = ((size_t)(b * 2 + g) * 64 + nw) * 1024 + rc0 + lane;
        float rowf = rows_[cbase];
        float colf = cols_[cbase];
        float r0f = floorf(rowf), c0f = floorf(colf);
        float wr = rowf - r0f, wc = colf - c0f;
        int r0 = (int)r0f, c0 = (int)c0f;
        bool rv0 = ((unsigned)r0 < 64u), rv1 = ((unsigned)(r0 + 1) < 64u);
        bool cv0 = ((unsigned)c0 < 64u), cv1 = ((unsigned)(c0 + 1) < 64u);
        float w00 = (rv0 && cv0) ? (1.f - wr) * (1.f - wc) : 0.f;
        float w01 = (rv0 && cv1) ? (1.f - wr) * wc : 0.f;
        float w10 = (rv1 && cv0) ? wr * (1.f - wc) : 0.f;
        float w11 = (rv1 && cv1) ? wr * wc : 0.f;
        int ra = min(max(r0, 0), 63), rb2 = min(max(r0 + 1, 0), 63);
        int ca = min(max(c0, 0), 63), cb2 = min(max(c0 + 1, 0), 63);
        size_t pb = ((size_t)g * 8192 + (size_t)b * 4096) * 256 + qc0 + w * 8;
        size_t o00 = pb + (size_t)(ra * 64 + ca) * 256;
        size_t o01 = pb + (size_t)(ra * 64 + cb2) * 256;
        size_t o10 = pb + (size_t)(rb2 * 64 + ca) * 256;
        size_t o11 = pb + (size_t)(rb2 * 64 + cb2) * 256;
        U16x8 k00, k01, k10, k11, v00, v01, v10, v11;
        k00.u4 = *(const uint4*)(Kimg + o00); v00.u4 = *(const uint4*)(Vimg + o00);
        k01.u4 = *(const uint4*)(Kimg + o01); v01.u4 = *(const uint4*)(Vimg + o01);
        k10.u4 = *(const uint4*)(Kimg + o10); v10.u4 = *(const uint4*)(Vimg + o10);
        k11.u4 = *(const uint4*)(Kimg + o11); v11.u4 = *(const uint4*)(Vimg + o11);
#pragma unroll
        for (int j = 0; j < 8; ++j) {
          aK[j] += w00 * b2f(k00.us[j]) + w01 * b2f(k01.us[j])
                 + w10 * b2f(k10.us[j]) + w11 * b2f(k11.us[j]);
          aV[j] += w00 * b2f(v00.us[j]) + w01 * b2f(v01.us[j])
                 + w10 * b2f(v10.us[j]) + w11 * b2f(v11.us[j]);
        }
      }
      U16x8 ok;
#pragma unroll
      for (int j = 0; j < 8; ++j) ok.us[j] = f2b(aK[j]);
      *(uint4*)&ks[lane][w * 8] = ok.u4;
#pragma unroll
      for (int j = 0; j < 8; ++j) vs[w * 8 + j][lane] = f2b(aV[j]);  // transposed
    }
    __syncthreads();

    // ---- S = Q.K^T via 4 MFMAs ----
    f32x4 s[4];
#pragma unroll
    for (int nt = 0; nt < 4; ++nt) {
      uint4 u = *(const uint4*)&ks[nt * 16 + l15][quad * 8];
      bf16x8 bK = __builtin_bit_cast(bf16x8, u);
      f32x4 z = (f32x4){0.f, 0.f, 0.f, 0.f};
      s[nt] = __builtin_amdgcn_mfma_f32_16x16x32_bf16(aQ, bK, z, 0, 0, 0);
    }
#pragma unroll
    for (int nt = 0; nt < 4; ++nt) {
      int rg_ = nt * 16 + l15;
      int rrow = (rc0 + rg_) >> 5, rcol = rg_ & 31;
#pragma unroll
      for (int reg = 0; reg < 4; ++reg) {
        int q = w * 16 + quad * 4 + reg;
        s[nt][reg] += b2f(pesb[2 * rrow + 7 - (q >> 3)][2 * rcol + 7 - (q & 7)]);
      }
    }
    // ---- online softmax (quad-local state) ----
    float alpha[4];
#pragma unroll
    for (int reg = 0; reg < 4; ++reg) {
      float mx = fmaxf(fmaxf(s[0][reg], s[1][reg]), fmaxf(s[2][reg], s[3][reg]));
      mx = fmaxf(mx, __shfl_xor(mx, 1, 64));
      mx = fmaxf(mx, __shfl_xor(mx, 2, 64));
      mx = fmaxf(mx, __shfl_xor(mx, 4, 64));
      mx = fmaxf(mx, __shfl_xor(mx, 8, 64));
      float mn = fmaxf(m[reg], mx);
      alpha[reg] = __expf(m[reg] - mn);
      m[reg] = mn;
      float ps = 0.f;
#pragma unroll
      for (int nt = 0; nt < 4; ++nt) {
        float p = __expf(s[nt][reg] - mn);
        PsQs[w * 16 + quad * 4 + reg][nt * 16 + l15] = f2b(p);
        ps += p;
      }
      ps += __shfl_xor(ps, 1, 64);
      ps += __shfl_xor(ps, 2, 64);
      ps += __shfl_xor(ps, 4, 64);
      ps += __shfl_xor(ps, 8, 64);
      l[reg] = l[reg] * alpha[reg] + ps;
      oacc[0][reg] *= alpha[reg];
      oacc[1][reg] *= alpha[reg];
    }
    // ---- O += P.V ----
#pragma unroll
    for (int kst = 0; kst < 2; ++kst) {
      uint4 up = *(const uint4*)&PsQs[w * 16 + l15][kst * 32 + quad * 8];
      bf16x8 pA = __builtin_bit_cast(bf16x8, up);
#pragma unroll
      for (int nt2 = 0; nt2 < 2; ++nt2) {
        uint4 uv = *(const uint4*)&vs[nt2 * 16 + l15][kst * 32 + quad * 8];
        bf16x8 vB = __builtin_bit_cast(bf16x8, uv);
        oacc[nt2] = __builtin_amdgcn_mfma_f32_16x16x32_bf16(pA, vB, oacc[nt2], 0, 0, 0);
      }
    }
    __syncthreads();
  }
  // epilogue: O/l + v_b, NHWC writes
#pragma unroll
  for (int nt2 = 0; nt2 < 2; ++nt2) {
    float vbias = vbv[qc0 + nt2 * 16 + l15];
#pragma unroll
    for (int reg = 0; reg < 4; ++reg) {
      int q = w * 16 + quad * 4 + reg;
      size_t p = (size_t)b * 4096 + (wh * 8 + (q >> 3)) * 64 + ww * 8 + (q & 7);
      aout[p * 256 + qc0 + nt2 * 16 + l15] =
          __float2bfloat16(oacc[nt2][reg] / l[reg] + vbias);
    }
  }
}

// ---------------------------------------------------------------------------
extern "C" void kernel_launch(void* const* d_in, const int* in_sizes, int n_in,
                              void* d_out, int out_size, void* d_ws, size_t ws_size,
                              hipStream_t stream) {
  (void)in_sizes; (void)n_in; (void)out_size; (void)ws_size;
  const float* x     = (const float*)d_in[0];
  const float* ln1g  = (const float*)d_in[1];
  const float* ln1b  = (const float*)d_in[2];
  const float* q_w   = (const float*)d_in[3];
  const float* q_b   = (const float*)d_in[4];
  const float* k_w   = (const float*)d_in[5];
  const float* k_b   = (const float*)d_in[6];
  const float* v_w   = (const float*)d_in[7];
  const float* v_b   = (const float*)d_in[8];
  const float* off1w = (const float*)d_in[9];
  const float* off2w = (const float*)d_in[10];
  const float* off3w = (const float*)d_in[11];
  const float* bng   = (const float*)d_in[12];
  const float* bnb   = (const float*)d_in[13];
  const float* bnm   = (const float*)d_in[14];
  const float* bnv   = (const float*)d_in[15];
  const float* off4w = (const float*)d_in[16];
  const float* pe    = (const float*)d_in[17];
  const float* pjw   = (const float*)d_in[18];
  const float* pjb   = (const float*)d_in[19];
  const float* ln2g  = (const float*)d_in[20];
  const float* ln2b  = (const float*)d_in[21];
  const float* w1    = (const float*)d_in[22];
  const float* b1    = (const float*)d_in[23];
  const float* w2    = (const float*)d_in[24];
  const float* b2    = (const float*)d_in[25];
  (void)k_b;
  float* outp = (float*)d_out;

  // workspace arena (~42 MB), all offsets 16B-aligned; act buffers NHWC
  char* W = (char*)d_ws;
  bf16*  xa    = (bf16*) (W + 0);          // [8192][256] bf16; reused as aout
  bf16*  qb    = (bf16*) (W + 4194304);    // [8192][256]; reused as xm
  float* dw1   = (float*)(W + 8388608);    // [4][1024][128] f32
  float* dw2   = (float*)(W + 10485760);   // [4][256][128] f32
  bf16*  dw3b  = (bf16*) (W + 11010048);   // [4][64][128] bf16
  float* rows  = (float*)(W + 11141120);   // [4][64][1024] f32
  float* cols  = (float*)(W + 12189696);   // [4][64][1024] f32
  bf16*  Kimg  = (bf16*) (W + 13238272);   // [2g][8192][256] bf16
  bf16*  Vimg  = (bf16*) (W + 21626880);   // [2g][8192][256]
  bf16*  x2    = (bf16*) (W + 30015488);   // [8192][256]
  float* xnhwc = (float*)(W + 34209792);   // [8192][256] f32 raw x
  bf16*  aout = xa;
  bf16*  xm   = qb;
  bf16*  hdn  = Kimg;                      // [8192][1024] over Kimg+Vimg (dead)

  // 1. LN1 (NCHW f32 -> NHWC bf16) + raw x transpose (f32 NHWC)
  ln1_kernel<<<256, 256, 0, stream>>>(x, ln1g, ln1b, xa, xnhwc);
  // 2. q = xa @ q_w^T + q_b
  mgemm_kernel<0, 0, 0><<<dim3(4, 64), 256, 0, stream>>>(
      xa, q_w, q_b, nullptr, qb, 256, 256, 256, 256);
  // 3. offset branch (NHWC-128); dw3 output bf16
  dwconv_kernel<bf16, float, 256><<<2048, 256, 0, stream>>>(
      qb, off1w, dw1, 64, 64, 32, 32, 0, nullptr, nullptr, nullptr, nullptr);
  dwconv_kernel<float, float, 128><<<512, 256, 0, stream>>>(
      dw1, off2w, dw2, 32, 32, 16, 16, 0, nullptr, nullptr, nullptr, nullptr);
  dwconv_kernel<float, bf16, 128><<<128, 256, 0, stream>>>(
      dw2, off3w, dw3b, 16, 16, 8, 8, 1, bng, bnb, bnm, bnv);
  // 4. offset head as MFMA GEMM: M=256 (bg*nw), N=2048 (coord*r), K=128
  mgemm_kernel<3, 0, 0><<<dim3(32, 2), 256, 0, stream>>>(
      dw3b, off4w, nullptr, (const void*)cols, rows, 2048, 128, 128, 128);
  // 5. Kimg/Vimg per group
  mgemm_kernel<0, 0, 0><<<dim3(4, 64), 256, 0, stream>>>(
      xa,       k_w,       nullptr, nullptr, Kimg,           256, 128, 256, 256);
  mgemm_kernel<0, 0, 0><<<dim3(4, 64), 256, 0, stream>>>(
      xa + 128, k_w + 128, nullptr, nullptr, Kimg + 2097152, 256, 128, 256, 256);
  mgemm_kernel<0, 0, 0><<<dim3(4, 64), 256, 0, stream>>>(
      xa,       v_w,       nullptr, nullptr, Vimg,           256, 128, 256, 256);
  mgemm_kernel<0, 0, 0><<<dim3(4, 64), 256, 0, stream>>>(
      xa + 128, v_w + 128, nullptr, nullptr, Vimg + 2097152, 256, 128, 256, 256);
  // 6. fused attention (in-kernel gather)
  attn_kernel<<<1024, 256, 0, stream>>>(
      qb, (const unsigned short*)Kimg, (const unsigned short*)Vimg,
      rows, cols, v_b, pe, aout);
  // 7. proj + residual(x_nhwc f32, coalesced) -> x2 NHWC bf16
  mgemm_kernel<0, 1, 0><<<dim3(4, 64), 256, 0, stream>>>(
      aout, pjw, pjb, (const void*)xnhwc, x2, 256, 256, 256, 256);
  // 8. LN2
  ln2_kernel<<<256, 256, 0, stream>>>(x2, ln2g, ln2b, xm);
  // 9. MLP1 + GELU
  mgemm_kernel<0, 0, 1><<<dim3(16, 64), 256, 0, stream>>>(
      xm, w1, b1, nullptr, hdn, 1024, 256, 256, 256);
  // 10. MLP2 + residual(x2) -> f32 NCHW d_out via LDS transpose
  mgemm_kernel<1, 2, 0><<<dim3(4, 64), 256, 0, stream>>>(
      hdn, w2, b2, (const void*)x2, outp, 256, 1024, 1024, 1024);
}

// Round 8
// 318.989 us; speedup vs baseline: 4.2956x; 1.2731x over previous
//
#include <hip/hip_runtime.h>
#include <hip/hip_bf16.h>
#include <math.h>

// CBiAFormerBlock fused implementation, round 8.
// Changes vs r7 (PASS, 406us; attn regressed 139->216us):
//  - attn gather mapping REVERTED to r6 style (t&3=8ch-seg, t>>2=r): 4 lanes
//    cover a contiguous 64B slice per corner -> coalesced requests (r7's
//    lane=r mapping made every load an isolated 16B from a random line).
//  - attn software pipeline: next chunk's 16 corner uint4 loads + 8 weights
//    held in registers across the MFMA/softmax phase; ks/vs double-buffered;
//    ONE barrier per chunk at loop top (issue AFTER barrier so the compiler's
//    pre-barrier vmcnt(0) drain doesn't flush the pipeline).
//  - XCD swizzle: b = blk&1 (round-robin blk%8 -> each XCD sees one batch's
//    8MB K+V instead of 16MB -> fewer L2 misses).
// mgemm/LN/dwconv/offgrid-fusion unchanged from r7 (that family improved).

typedef __hip_bfloat16 bf16;
typedef __bf16 bf16x8 __attribute__((ext_vector_type(8)));
typedef float f32x4 __attribute__((ext_vector_type(4)));

union U16x8 { uint4 u4; unsigned short us[8]; };

__device__ __forceinline__ float cvt(float x) { return x; }
__device__ __forceinline__ float cvt(bf16 x) { return __bfloat162float(x); }
__device__ __forceinline__ float b2f(unsigned short u) {
  union { float f; unsigned int v; } x; x.v = ((unsigned int)u) << 16; return x.f;
}
__device__ __forceinline__ unsigned short f2b(float f) {
  bf16 h = __float2bfloat16(f);
  return *reinterpret_cast<unsigned short*>(&h);
}
__device__ __forceinline__ float gelu_f(float x) {
  return 0.5f * x * (1.0f + erff(x * 0.7071067811865475f));
}
__device__ __forceinline__ void stout(float* p, float v) { *p = v; }
__device__ __forceinline__ void stout(bf16* p, float v) { *p = __float2bfloat16(v); }

// ---------------- LN1: NCHW f32 in -> NHWC bf16 out + raw x NHWC f32 -------
__global__ __launch_bounds__(256) void ln1_kernel(
    const float* __restrict__ x, const float* __restrict__ g,
    const float* __restrict__ bta, bf16* __restrict__ out,
    float* __restrict__ xnhwc)
{
  __shared__ float s1[8][32], s2[8][32];
  __shared__ unsigned short tb[32][264];
  int t = threadIdx.x;
  int pos = t & 31, cs = t >> 5;
  int p = blockIdx.x * 32 + pos;
  int bb = p >> 12, hw = p & 4095;
  const float* xp = x + (size_t)bb * 256 * 4096 + hw;
  float vloc[32];
  float sum = 0.f, ss = 0.f;
#pragma unroll
  for (int i = 0; i < 32; ++i) {
    float v = xp[(size_t)(cs * 32 + i) * 4096];
    vloc[i] = v; sum += v; ss += v * v;
  }
  s1[cs][pos] = sum; s2[cs][pos] = ss;
  {
    float* xo = xnhwc + (size_t)p * 256 + cs * 32;
#pragma unroll
    for (int qd = 0; qd < 8; ++qd)
      *(float4*)(xo + qd * 4) = make_float4(vloc[qd*4], vloc[qd*4+1],
                                            vloc[qd*4+2], vloc[qd*4+3]);
  }
  __syncthreads();
  if (cs == 0) {
    float S = 0.f, Q = 0.f;
#pragma unroll
    for (int i = 0; i < 8; ++i) { S += s1[i][pos]; Q += s2[i][pos]; }
    float mu = S * (1.f / 256.f);
    float var = Q * (1.f / 256.f) - mu * mu;
    s1[0][pos] = mu;
    s2[0][pos] = rsqrtf(var + 1e-5f);
  }
  __syncthreads();
  float mu = s1[0][pos], rs = s2[0][pos];
#pragma unroll
  for (int i = 0; i < 32; ++i) {
    int c = cs * 32 + i;
    tb[pos][c] = f2b((vloc[i] - mu) * rs * g[c] + bta[c]);
  }
  __syncthreads();
  int px = t >> 3, grp = t & 7;
  bf16* op = out + ((size_t)blockIdx.x * 32 + px) * 256 + grp * 32;
#pragma unroll
  for (int q = 0; q < 4; ++q)
    *(uint4*)(op + q * 8) = *(const uint4*)&tb[px][grp * 32 + q * 8];
}

// ---------------- LN2: NHWC bf16 in -> NHWC bf16 out -----------------------
__global__ __launch_bounds__(256) void ln2_kernel(
    const bf16* __restrict__ xin, const float* __restrict__ g,
    const float* __restrict__ bta, bf16* __restrict__ out)
{
  __shared__ float sa[8][32], sb[8][32];
  __shared__ float mu_s[32], rs_s[32];
  int t = threadIdx.x;
  int px = t >> 3, grp = t & 7;
  size_t p = (size_t)blockIdx.x * 32 + px;
  const bf16* xp = xin + p * 256 + grp * 32;
  float v[32]; float sum = 0.f, ss = 0.f;
#pragma unroll
  for (int q = 0; q < 4; ++q) {
    U16x8 u; u.u4 = *(const uint4*)(xp + q * 8);
#pragma unroll
    for (int j = 0; j < 8; ++j) {
      float f = b2f(u.us[j]); v[q * 8 + j] = f; sum += f; ss += f * f;
    }
  }
  sa[grp][px] = sum; sb[grp][px] = ss;
  __syncthreads();
  if (t < 32) {
    float S = 0.f, Q = 0.f;
#pragma unroll
    for (int i = 0; i < 8; ++i) { S += sa[i][t]; Q += sb[i][t]; }
    float mu = S * (1.f / 256.f);
    mu_s[t] = mu;
    rs_s[t] = rsqrtf(Q * (1.f / 256.f) - mu * mu + 1e-5f);
  }
  __syncthreads();
  float mu = mu_s[px], rs = rs_s[px];
  bf16* op = out + p * 256 + grp * 32;
#pragma unroll
  for (int q = 0; q < 4; ++q) {
    U16x8 o;
#pragma unroll
    for (int j = 0; j < 8; ++j) {
      int c = grp * 32 + q * 8 + j;
      o.us[j] = f2b((v[q * 8 + j] - mu) * rs * g[c] + bta[c]);
    }
    *(uint4*)(op + q * 8) = o.u4;
  }
}

// ---------------- MFMA GEMM (NHWC): out[p][o] = sum_c A[p][c] W[o][c] ------
// BM=128, BN=64, BK=64; grid (N/64, M/128); 4 waves as 2x2 (64m x 32n each).
template<int OUTM, int RESM, int ACT>
__global__ __launch_bounds__(256) void mgemm_kernel(
    const bf16* __restrict__ A, const float* __restrict__ Bw,
    const float* __restrict__ bias, const void* __restrict__ res,
    void* __restrict__ out, int N, int K, int lda, int ldb)
{
  constexpr int AB_BYTES = (128 * 72 + 64 * 72) * 2;
  constexpr int T_BYTES  = 64 * 133 * 4;
  constexpr int SH_BYTES = (OUTM == 1 && T_BYTES > AB_BYTES) ? T_BYTES : AB_BYTES;
  __shared__ __attribute__((aligned(16))) char shraw[SH_BYTES];
  auto As = reinterpret_cast<unsigned short(*)[72]>(shraw);
  auto Bs = reinterpret_cast<unsigned short(*)[72]>(shraw + 128 * 72 * 2);
  float (*T)[133] = reinterpret_cast<float(*)[133]>(shraw);

  int t = threadIdx.x;
  int m0 = blockIdx.y * 128, n0 = blockIdx.x * 64;
  int lane = t & 63, w = t >> 6;
  int l15 = lane & 15, quad = lane >> 4;
  int wm = (w >> 1) * 64, wn = (w & 1) * 32;
  f32x4 acc[4][2];
#pragma unroll
  for (int mt = 0; mt < 4; ++mt)
#pragma unroll
    for (int nt = 0; nt < 2; ++nt) acc[mt][nt] = (f32x4){0.f, 0.f, 0.f, 0.f};

  for (int k0 = 0; k0 < K; k0 += 64) {
#pragma unroll
    for (int i = 0; i < 4; ++i) {
      int idx = t + i * 256;
      int m = idx >> 3, oc = (idx & 7) * 8;
      *(uint4*)&As[m][oc] = *(const uint4*)(A + (size_t)(m0 + m) * lda + k0 + oc);
    }
    {
      int n = t >> 2, h = (t & 3) * 16;
      const float* bp = Bw + (size_t)(n0 + n) * ldb + k0 + h;
      float4 f0 = *(const float4*)(bp);
      float4 f1 = *(const float4*)(bp + 4);
      float4 f2 = *(const float4*)(bp + 8);
      float4 f3 = *(const float4*)(bp + 12);
      U16x8 u0, u1;
      u0.us[0] = f2b(f0.x); u0.us[1] = f2b(f0.y); u0.us[2] = f2b(f0.z); u0.us[3] = f2b(f0.w);
      u0.us[4] = f2b(f1.x); u0.us[5] = f2b(f1.y); u0.us[6] = f2b(f1.z); u0.us[7] = f2b(f1.w);
      u1.us[0] = f2b(f2.x); u1.us[1] = f2b(f2.y); u1.us[2] = f2b(f2.z); u1.us[3] = f2b(f2.w);
      u1.us[4] = f2b(f3.x); u1.us[5] = f2b(f3.y); u1.us[6] = f2b(f3.z); u1.us[7] = f2b(f3.w);
      *(uint4*)&Bs[n][h] = u0.u4;
      *(uint4*)&Bs[n][h + 8] = u1.u4;
    }
    __syncthreads();
#pragma unroll
    for (int ks = 0; ks < 2; ++ks) {
      bf16x8 af[4], bfr[2];
#pragma unroll
      for (int mt = 0; mt < 4; ++mt)
        af[mt] = __builtin_bit_cast(bf16x8,
            *(const uint4*)&As[wm + mt * 16 + l15][ks * 32 + quad * 8]);
#pragma unroll
      for (int nt = 0; nt < 2; ++nt)
        bfr[nt] = __builtin_bit_cast(bf16x8,
            *(const uint4*)&Bs[wn + nt * 16 + l15][ks * 32 + quad * 8]);
#pragma unroll
      for (int mt = 0; mt < 4; ++mt)
#pragma unroll
        for (int nt = 0; nt < 2; ++nt)
          acc[mt][nt] = __builtin_amdgcn_mfma_f32_16x16x32_bf16(
              af[mt], bfr[nt], acc[mt][nt], 0, 0, 0);
    }
    __syncthreads();
  }
  float bv[2];
#pragma unroll
  for (int nt = 0; nt < 2; ++nt)
    bv[nt] = bias ? bias[n0 + wn + nt * 16 + l15] : 0.f;
#pragma unroll
  for (int mt = 0; mt < 4; ++mt) {
#pragma unroll
    for (int nt = 0; nt < 2; ++nt) {
#pragma unroll
      for (int reg = 0; reg < 4; ++reg) {
        int m = m0 + wm + mt * 16 + quad * 4 + reg;
        int n = n0 + wn + nt * 16 + l15;
        float v = acc[mt][nt][reg] + bv[nt];
        if constexpr (ACT == 1) v = gelu_f(v);
        if constexpr (RESM == 1)
          v += ((const float*)res)[(size_t)m * N + n];
        if constexpr (RESM == 2)
          v += b2f(((const unsigned short*)res)[(size_t)m * N + n]);
        if constexpr (OUTM == 0)
          ((unsigned short*)out)[(size_t)m * N + n] = f2b(v);
        if constexpr (OUTM == 1)
          T[(n - n0)][(m - m0)] = v;
        if constexpr (OUTM == 3) {
          float val = tanhf(v) * (2.0f / 64.0f);
          int coord = n >> 10, r = n & 1023;
          int rc = coord ? (r & 31) : (r >> 5);
          float ref = rc * (4.0f / 63.0f) - 1.0f;
          float pix = (val + ref + 1.0f) * 31.5f;
          float* dst = coord ? (float*)res : (float*)out;
          dst[(size_t)m * 1024 + r] = pix;
        }
      }
    }
  }
  if constexpr (OUTM == 1) {
    __syncthreads();
    int nl = t >> 2, seg = t & 3;
    int bI = m0 >> 12, hw0 = m0 & 4095;
    float* op = (float*)out + ((size_t)bI * 256 + n0 + nl) * 4096 + hw0 + seg * 32;
#pragma unroll
    for (int k = 0; k < 32; ++k) op[k] = T[nl][seg * 32 + k];
  }
}

// ---------------- depthwise 3x3 stride-2 pad-1 conv, NHWC-128 --------------
template<typename TI, typename TO, int IC>
__global__ __launch_bounds__(256) void dwconv_kernel(
    const TI* __restrict__ in, const float* __restrict__ wgt,
    TO* __restrict__ out, int Hi, int Wi, int Ho, int Wo, int fuse,
    const float* __restrict__ bg_, const float* __restrict__ bb_,
    const float* __restrict__ bm_, const float* __restrict__ bv_)
{
  int idx = blockIdx.x * 256 + threadIdx.x;
  int c = idx & 127;
  int pp = idx >> 7;
  int ow = pp % Wo, oh = (pp / Wo) % Ho, bgi = pp / (Wo * Ho);
  const TI* ip;
  if constexpr (IC == 256)
    ip = in + ((size_t)(bgi >> 1) * 4096) * 256 + (bgi & 1) * 128 + c;
  else
    ip = in + ((size_t)bgi * Hi * Wi) * 128 + c;
  float acc = 0.f;
#pragma unroll
  for (int ky = 0; ky < 3; ++ky) {
    int ih = oh * 2 - 1 + ky;
    if ((unsigned)ih >= (unsigned)Hi) continue;
#pragma unroll
    for (int kx = 0; kx < 3; ++kx) {
      int iw = ow * 2 - 1 + kx;
      if ((unsigned)iw >= (unsigned)Wi) continue;
      acc += wgt[c * 9 + ky * 3 + kx] * cvt(ip[(size_t)(ih * Wi + iw) * IC]);
    }
  }
  if (fuse) {
    acc = (acc - bm_[c]) * rsqrtf(bv_[c] + 1e-5f) * bg_[c] + bb_[c];
    acc = gelu_f(acc);
  }
  stout(out + idx, acc);
}

// ---------------- attn helpers: pipelined bilinear gather ------------------
__device__ __forceinline__ void gather_issue(
    int rc0, int b, int nw, int gr_r, int choff,
    const float* __restrict__ rows_, const float* __restrict__ cols_,
    const unsigned short* __restrict__ Kimg, const unsigned short* __restrict__ Vimg,
    uint4* kc, uint4* vc, float* wgt)
{
#pragma unroll
  for (int g = 0; g < 2; ++g) {
    size_t cbase = ((size_t)(b * 2 + g) * 64 + nw) * 1024 + rc0 + gr_r;
    float rowf = rows_[cbase];
    float colf = cols_[cbase];
    float r0f = floorf(rowf), c0f = floorf(colf);
    float wr = rowf - r0f, wc = colf - c0f;
    int r0 = (int)r0f, c0 = (int)c0f;
    bool rv0 = ((unsigned)r0 < 64u), rv1 = ((unsigned)(r0 + 1) < 64u);
    bool cv0 = ((unsigned)c0 < 64u), cv1 = ((unsigned)(c0 + 1) < 64u);
    wgt[g * 4 + 0] = (rv0 && cv0) ? (1.f - wr) * (1.f - wc) : 0.f;
    wgt[g * 4 + 1] = (rv0 && cv1) ? (1.f - wr) * wc : 0.f;
    wgt[g * 4 + 2] = (rv1 && cv0) ? wr * (1.f - wc) : 0.f;
    wgt[g * 4 + 3] = (rv1 && cv1) ? wr * wc : 0.f;
    int ra = min(max(r0, 0), 63), rb2 = min(max(r0 + 1, 0), 63);
    int ca = min(max(c0, 0), 63), cb2 = min(max(c0 + 1, 0), 63);
    size_t pb = ((size_t)g * 8192 + (size_t)b * 4096) * 256 + choff;
    size_t o00 = pb + (size_t)(ra * 64 + ca) * 256;
    size_t o01 = pb + (size_t)(ra * 64 + cb2) * 256;
    size_t o10 = pb + (size_t)(rb2 * 64 + ca) * 256;
    size_t o11 = pb + (size_t)(rb2 * 64 + cb2) * 256;
    kc[g * 4 + 0] = *(const uint4*)(Kimg + o00); vc[g * 4 + 0] = *(const uint4*)(Vimg + o00);
    kc[g * 4 + 1] = *(const uint4*)(Kimg + o01); vc[g * 4 + 1] = *(const uint4*)(Vimg + o01);
    kc[g * 4 + 2] = *(const uint4*)(Kimg + o10); vc[g * 4 + 2] = *(const uint4*)(Vimg + o10);
    kc[g * 4 + 3] = *(const uint4*)(Kimg + o11); vc[g * 4 + 3] = *(const uint4*)(Vimg + o11);
  }
}

// ---------------- MFMA fused deformable window attention (pipelined) -------
// One block per (b, head, nw); b = blk&1 (XCD affinity). Gather mapping:
// gr_r = t>>2, gr_seg = t&3 (4 lanes cover contiguous 64B per corner).
__global__ __launch_bounds__(256) void attn_kernel(
    const bf16* __restrict__ qbuf, const unsigned short* __restrict__ Kimg,
    const unsigned short* __restrict__ Vimg, const float* __restrict__ rows_,
    const float* __restrict__ cols_, const float* __restrict__ vbv,
    const float* __restrict__ pe, bf16* __restrict__ aout)
{
  __shared__ unsigned short ks[2][64][40];    // 10240 B
  __shared__ unsigned short vs[2][32][80];    // 10240 B (transposed V)
  __shared__ unsigned short PsQs[64][72];     // 9216 B
  __shared__ unsigned short pesb[70][72];     // 10080 B
  // total 39,776 B

  int blk = blockIdx.x;
  int b = blk & 1, head = (blk >> 1) & 7, nw = blk >> 4;
  int wh = nw >> 3, ww = nw & 7;
  int t = threadIdx.x;
  int lane = t & 63, w = t >> 6;
  int l15 = lane & 15, quad = lane >> 4;
  int qc0 = head * 32;
  int gr_r = t >> 2, gr_seg = t & 3;
  int choff = qc0 + gr_seg * 8;

  // stage Q (scaled 1/16) into PsQs
  {
    int qt = t >> 2, oct = t & 3;
    int h = wh * 8 + (qt >> 3), wcol = ww * 8 + (qt & 7);
    const bf16* src = qbuf + ((size_t)b * 4096 + h * 64 + wcol) * 256 + qc0 + oct * 8;
    U16x8 u; u.u4 = *(const uint4*)src;
    U16x8 o;
#pragma unroll
    for (int j = 0; j < 8; ++j) o.us[j] = f2b(b2f(u.us[j]) * 0.0625f);
    *(uint4*)&PsQs[qt][oct * 8] = o.u4;
  }
  int ry0 = 56 - wh * 8, rx0 = 56 - ww * 8;
  for (int i = t; i < 70 * 70; i += 256) {
    int yy = i / 70, xx = i % 70;
    pesb[yy][xx] = f2b(pe[(size_t)head * 16129 + (ry0 + yy) * 127 + rx0 + xx]);
  }

  uint4 kc[8], vc[8];
  float wgt[8];
  // prologue: gather chunk 0 into buf 0
  gather_issue(0, b, nw, gr_r, choff, rows_, cols_, Kimg, Vimg, kc, vc, wgt);
  {
    float aK[8] = {0,0,0,0,0,0,0,0}, aV[8] = {0,0,0,0,0,0,0,0};
#pragma unroll
    for (int gc = 0; gc < 8; ++gc) {
      U16x8 ku, vu; ku.u4 = kc[gc]; vu.u4 = vc[gc];
      float wv = wgt[gc];
#pragma unroll
      for (int j = 0; j < 8; ++j) { aK[j] += wv * b2f(ku.us[j]); aV[j] += wv * b2f(vu.us[j]); }
    }
    U16x8 ok;
#pragma unroll
    for (int j = 0; j < 8; ++j) ok.us[j] = f2b(aK[j]);
    *(uint4*)&ks[0][gr_r][gr_seg * 8] = ok.u4;
#pragma unroll
    for (int j = 0; j < 8; ++j) vs[0][gr_seg * 8 + j][gr_r] = f2b(aV[j]);
  }
  __syncthreads();   // Q, pes, buf0 all visible

  bf16x8 aQ;
  {
    uint4 u = *(const uint4*)&PsQs[w * 16 + l15][quad * 8];
    aQ = __builtin_bit_cast(bf16x8, u);
  }
  float m[4] = {-1e30f, -1e30f, -1e30f, -1e30f};
  float l[4] = {0.f, 0.f, 0.f, 0.f};
  f32x4 oacc[2];
  oacc[0] = (f32x4){0.f, 0.f, 0.f, 0.f};
  oacc[1] = (f32x4){0.f, 0.f, 0.f, 0.f};

  for (int c = 0; c < 16; ++c) {
    if (c) __syncthreads();          // buf[cur] committed by all waves
    int cur = c & 1, rc0 = c * 64;
    // issue next chunk's loads AFTER the barrier (stay in flight thru compute)
    if (c < 15)
      gather_issue(rc0 + 64, b, nw, gr_r, choff, rows_, cols_, Kimg, Vimg, kc, vc, wgt);

    // ---- S = Q.K^T via 4 MFMAs ----
    f32x4 s[4];
#pragma unroll
    for (int nt = 0; nt < 4; ++nt) {
      uint4 u = *(const uint4*)&ks[cur][nt * 16 + l15][quad * 8];
      bf16x8 bK = __builtin_bit_cast(bf16x8, u);
      f32x4 z = (f32x4){0.f, 0.f, 0.f, 0.f};
      s[nt] = __builtin_amdgcn_mfma_f32_16x16x32_bf16(aQ, bK, z, 0, 0, 0);
    }
#pragma unroll
    for (int nt = 0; nt < 4; ++nt) {
      int rg_ = nt * 16 + l15;
      int rrow = (rc0 + rg_) >> 5, rcol = rg_ & 31;
#pragma unroll
      for (int reg = 0; reg < 4; ++reg) {
        int q = w * 16 + quad * 4 + reg;
        s[nt][reg] += b2f(pesb[2 * rrow + 7 - (q >> 3)][2 * rcol + 7 - (q & 7)]);
      }
    }
    // ---- online softmax (quad-local state) ----
    float alpha[4];
#pragma unroll
    for (int reg = 0; reg < 4; ++reg) {
      float mx = fmaxf(fmaxf(s[0][reg], s[1][reg]), fmaxf(s[2][reg], s[3][reg]));
      mx = fmaxf(mx, __shfl_xor(mx, 1, 64));
      mx = fmaxf(mx, __shfl_xor(mx, 2, 64));
      mx = fmaxf(mx, __shfl_xor(mx, 4, 64));
      mx = fmaxf(mx, __shfl_xor(mx, 8, 64));
      float mn = fmaxf(m[reg], mx);
      alpha[reg] = __expf(m[reg] - mn);
      m[reg] = mn;
      float ps = 0.f;
#pragma unroll
      for (int nt = 0; nt < 4; ++nt) {
        float p = __expf(s[nt][reg] - mn);
        PsQs[w * 16 + quad * 4 + reg][nt * 16 + l15] = f2b(p);
        ps += p;
      }
      ps += __shfl_xor(ps, 1, 64);
      ps += __shfl_xor(ps, 2, 64);
      ps += __shfl_xor(ps, 4, 64);
      ps += __shfl_xor(ps, 8, 64);
      l[reg] = l[reg] * alpha[reg] + ps;
      oacc[0][reg] *= alpha[reg];
      oacc[1][reg] *= alpha[reg];
    }
    // ---- O += P.V (Ps rows wave-local; no barrier needed) ----
#pragma unroll
    for (int kst = 0; kst < 2; ++kst) {
      uint4 up = *(const uint4*)&PsQs[w * 16 + l15][kst * 32 + quad * 8];
      bf16x8 pA = __builtin_bit_cast(bf16x8, up);
#pragma unroll
      for (int nt2 = 0; nt2 < 2; ++nt2) {
        uint4 uv = *(const uint4*)&vs[cur][nt2 * 16 + l15][kst * 32 + quad * 8];
        bf16x8 vB = __builtin_bit_cast(bf16x8, uv);
        oacc[nt2] = __builtin_amdgcn_mfma_f32_16x16x32_bf16(pA, vB, oacc[nt2], 0, 0, 0);
      }
    }
    // ---- commit next chunk into buf[cur^1] ----
    if (c < 15) {
      float aK[8] = {0,0,0,0,0,0,0,0}, aV[8] = {0,0,0,0,0,0,0,0};
#pragma unroll
      for (int gc = 0; gc < 8; ++gc) {
        U16x8 ku, vu; ku.u4 = kc[gc]; vu.u4 = vc[gc];
        float wv = wgt[gc];
#pragma unroll
        for (int j = 0; j < 8; ++j) { aK[j] += wv * b2f(ku.us[j]); aV[j] += wv * b2f(vu.us[j]); }
      }
      int nxt = cur ^ 1;
      U16x8 ok;
#pragma unroll
      for (int j = 0; j < 8; ++j) ok.us[j] = f2b(aK[j]);
      *(uint4*)&ks[nxt][gr_r][gr_seg * 8] = ok.u4;
#pragma unroll
      for (int j = 0; j < 8; ++j) vs[nxt][gr_seg * 8 + j][gr_r] = f2b(aV[j]);
    }
  }
  // epilogue: O/l + v_b, NHWC writes
#pragma unroll
  for (int nt2 = 0; nt2 < 2; ++nt2) {
    float vbias = vbv[qc0 + nt2 * 16 + l15];
#pragma unroll
    for (int reg = 0; reg < 4; ++reg) {
      int q = w * 16 + quad * 4 + reg;
      size_t p = (size_t)b * 4096 + (wh * 8 + (q >> 3)) * 64 + ww * 8 + (q & 7);
      aout[p * 256 + qc0 + nt2 * 16 + l15] =
          __float2bfloat16(oacc[nt2][reg] / l[reg] + vbias);
    }
  }
}

// ---------------------------------------------------------------------------
extern "C" void kernel_launch(void* const* d_in, const int* in_sizes, int n_in,
                              void* d_out, int out_size, void* d_ws, size_t ws_size,
                              hipStream_t stream) {
  (void)in_sizes; (void)n_in; (void)out_size; (void)ws_size;
  const float* x     = (const float*)d_in[0];
  const float* ln1g  = (const float*)d_in[1];
  const float* ln1b  = (const float*)d_in[2];
  const float* q_w   = (const float*)d_in[3];
  const float* q_b   = (const float*)d_in[4];
  const float* k_w   = (const float*)d_in[5];
  const float* k_b   = (const float*)d_in[6];
  const float* v_w   = (const float*)d_in[7];
  const float* v_b   = (const float*)d_in[8];
  const float* off1w = (const float*)d_in[9];
  const float* off2w = (const float*)d_in[10];
  const float* off3w = (const float*)d_in[11];
  const float* bng   = (const float*)d_in[12];
  const float* bnb   = (const float*)d_in[13];
  const float* bnm   = (const float*)d_in[14];
  const float* bnv   = (const float*)d_in[15];
  const float* off4w = (const float*)d_in[16];
  const float* pe    = (const float*)d_in[17];
  const float* pjw   = (const float*)d_in[18];
  const float* pjb   = (const float*)d_in[19];
  const float* ln2g  = (const float*)d_in[20];
  const float* ln2b  = (const float*)d_in[21];
  const float* w1    = (const float*)d_in[22];
  const float* b1    = (const float*)d_in[23];
  const float* w2    = (const float*)d_in[24];
  const float* b2    = (const float*)d_in[25];
  (void)k_b;
  float* outp = (float*)d_out;

  char* W = (char*)d_ws;
  bf16*  xa    = (bf16*) (W + 0);
  bf16*  qb    = (bf16*) (W + 4194304);
  float* dw1   = (float*)(W + 8388608);
  float* dw2   = (float*)(W + 10485760);
  bf16*  dw3b  = (bf16*) (W + 11010048);
  float* rows  = (float*)(W + 11141120);
  float* cols  = (float*)(W + 12189696);
  bf16*  Kimg  = (bf16*) (W + 13238272);
  bf16*  Vimg  = (bf16*) (W + 21626880);
  bf16*  x2    = (bf16*) (W + 30015488);
  float* xnhwc = (float*)(W + 34209792);
  bf16*  aout = xa;
  bf16*  xm   = qb;
  bf16*  hdn  = Kimg;

  // 1. LN1 (NCHW f32 -> NHWC bf16) + raw x transpose (f32 NHWC)
  ln1_kernel<<<256, 256, 0, stream>>>(x, ln1g, ln1b, xa, xnhwc);
  // 2. q = xa @ q_w^T + q_b
  mgemm_kernel<0, 0, 0><<<dim3(4, 64), 256, 0, stream>>>(
      xa, q_w, q_b, nullptr, qb, 256, 256, 256, 256);
  // 3. offset branch (NHWC-128); dw3 output bf16
  dwconv_kernel<bf16, float, 256><<<2048, 256, 0, stream>>>(
      qb, off1w, dw1, 64, 64, 32, 32, 0, nullptr, nullptr, nullptr, nullptr);
  dwconv_kernel<float, float, 128><<<512, 256, 0, stream>>>(
      dw1, off2w, dw2, 32, 32, 16, 16, 0, nullptr, nullptr, nullptr, nullptr);
  dwconv_kernel<float, bf16, 128><<<128, 256, 0, stream>>>(
      dw2, off3w, dw3b, 16, 16, 8, 8, 1, bng, bnb, bnm, bnv);
  // 4. offset head as MFMA GEMM (tanh+grid fused epilogue)
  mgemm_kernel<3, 0, 0><<<dim3(32, 2), 256, 0, stream>>>(
      dw3b, off4w, nullptr, (const void*)cols, rows, 2048, 128, 128, 128);
  // 5. Kimg/Vimg per group
  mgemm_kernel<0, 0, 0><<<dim3(4, 64), 256, 0, stream>>>(
      xa,       k_w,       nullptr, nullptr, Kimg,           256, 128, 256, 256);
  mgemm_kernel<0, 0, 0><<<dim3(4, 64), 256, 0, stream>>>(
      xa + 128, k_w + 128, nullptr, nullptr, Kimg + 2097152, 256, 128, 256, 256);
  mgemm_kernel<0, 0, 0><<<dim3(4, 64), 256, 0, stream>>>(
      xa,       v_w,       nullptr, nullptr, Vimg,           256, 128, 256, 256);
  mgemm_kernel<0, 0, 0><<<dim3(4, 64), 256, 0, stream>>>(
      xa + 128, v_w + 128, nullptr, nullptr, Vimg + 2097152, 256, 128, 256, 256);
  // 6. fused attention (pipelined in-kernel gather, XCD b-swizzle)
  attn_kernel<<<1024, 256, 0, stream>>>(
      qb, (const unsigned short*)Kimg, (const unsigned short*)Vimg,
      rows, cols, v_b, pe, aout);
  // 7. proj + residual(x_nhwc f32) -> x2 NHWC bf16
  mgemm_kernel<0, 1, 0><<<dim3(4, 64), 256, 0, stream>>>(
      aout, pjw, pjb, (const void*)xnhwc, x2, 256, 256, 256, 256);
  // 8. LN2
  ln2_kernel<<<256, 256, 0, stream>>>(x2, ln2g, ln2b, xm);
  // 9. MLP1 + GELU
  mgemm_kernel<0, 0, 1><<<dim3(16, 64), 256, 0, stream>>>(
      xm, w1, b1, nullptr, hdn, 1024, 256, 256, 256);
  // 10. MLP2 + residual(x2) -> f32 NCHW d_out via LDS transpose
  mgemm_kernel<1, 2, 0><<<dim3(4, 64), 256, 0, stream>>>(
      hdn, w2, b2, (const void*)x2, outp, 256, 1024, 1024, 1024);
}